// Round 9
// baseline (315.434 us; speedup 1.0000x reference)
//
#include <hip/hip_runtime.h>
#include <math.h>

constexpr int N_NODES = 100000;
constexpr int N_EDGES = 1600000;
constexpr int F_IN    = 128;
constexpr int F_H     = 64;
constexpr float NEG_SLOPE = 0.2f;

constexpr int NBUCK  = (N_NODES + 255) / 256;  // 391 buckets of 256 dst nodes
constexpr int BUFCAP = 6144;                   // per-bucket stream cap (mean 4092, +32 sigma)
constexpr int LCAP   = 6144;
constexpr int CPAD   = 16;                     // gcur stride in ints: one 64B line per counter

// staged multisplit params
constexpr int SB   = 256;                      // staging blocks (75KB LDS -> 2 blocks/CU, all CUs)
constexpr int EPT  = 4;                        // edges per thread per round
constexpr int EPR  = 256 * EPT;                // 1024 edges per round
constexpr int G    = 16;                       // flush granularity = one 64B line
constexpr int BCAP = 48;                       // LDS bin capacity (15 carry + Poisson(2.62) tail)

__device__ inline float lrelu(float v) { return v > 0.f ? v : NEG_SLOPE * v; }
// bf16-pair unpack: u32 holds [lo = feature 2i, hi = feature 2i+1]
__device__ inline float blo(unsigned u) { return __uint_as_float(u << 16); }
__device__ inline float bhi(unsigned u) { return __uint_as_float(u & 0xFFFF0000u); }
// RNE float->bf16 (as high 16 bits)
__device__ inline unsigned bf16hi(float f) {
    unsigned u = __float_as_uint(f);
    return (u + 0x7FFFu + ((u >> 16) & 1u)) & 0xFFFF0000u;
}
__device__ inline unsigned bf16lo(float f) {
    unsigned u = __float_as_uint(f);
    return (u + 0x7FFFu + ((u >> 16) & 1u)) >> 16;
}

// ---------------- GEMM: block = 64 rows, 4 waves split the 64 features (16 each) ----------------
// h1 now stored SLICE-PLANAR: plane s (s=0..7) holds features [8s,8s+8) of all nodes as 16B rows
// (4 u32 of bf16 pairs). Wave w (features 16w..16w+16) writes planes 2w and 2w+1. Coalesced:
// consecutive lanes = consecutive rows = consecutive 16B.
__global__ __launch_bounds__(256) void k_gemm1(
    const float* __restrict__ x, const float* __restrict__ W1,
    const float* __restrict__ a_s, const float* __restrict__ a_d,
    unsigned* __restrict__ h1b, float* __restrict__ as1, float* __restrict__ ad1)
{
    __shared__ float vsP[4][64];
    __shared__ float vdP[4][64];

    const int lane = threadIdx.x & 63;
    const int w    = __builtin_amdgcn_readfirstlane(threadIdx.x >> 6);  // SGPR wave id
    const int fo   = w * 16;                 // feature offset (wave-uniform)
    const int row  = blockIdx.x * 64 + lane;
    const bool valid = row < N_NODES;

    float acc[16];
#pragma unroll
    for (int i = 0; i < 16; ++i) acc[i] = 0.f;

    if (valid) {
        const float4* __restrict__ xr = (const float4*)(x + (size_t)row * F_IN);
        for (int k4 = 0; k4 < F_IN / 4; ++k4) {
            const float4 xv = xr[k4];
            const float* __restrict__ wk = W1 + (size_t)k4 * 4 * F_H + fo;  // wave-uniform
#pragma unroll
            for (int kk = 0; kk < 4; ++kk) {
                const float xs = (kk == 0) ? xv.x : (kk == 1) ? xv.y : (kk == 2) ? xv.z : xv.w;
                const float* __restrict__ ws = wk + kk * F_H;   // scalar loads (SGPR base)
#pragma unroll
                for (int i = 0; i < 16; ++i)
                    acc[i] = fmaf(xs, ws[i], acc[i]);
            }
        }
    }

    // partial alphas over this wave's 16 features (fp32, pre-rounding)
    float vs = 0.f, vd = 0.f;
#pragma unroll
    for (int i = 0; i < 16; ++i) {
        vs = fmaf(acc[i], a_s[fo + i], vs);
        vd = fmaf(acc[i], a_d[fo + i], vd);
    }
    vsP[w][lane] = vs;
    vdP[w][lane] = vd;
    __syncthreads();
    if (w == 0 && valid) {
        as1[row] = vsP[0][lane] + vsP[1][lane] + vsP[2][lane] + vsP[3][lane];
        ad1[row] = vdP[0][lane] + vdP[1][lane] + vdP[2][lane] + vdP[3][lane];
    }

    if (valid) {
        unsigned up[8];
#pragma unroll
        for (int i = 0; i < 8; ++i)
            up[i] = bf16lo(acc[2 * i]) | bf16hi(acc[2 * i + 1]);
        // plane 2w: features [16w,16w+8); plane 2w+1: features [16w+8,16w+16)
        *(uint4*)(h1b + ((size_t)(2 * w)     * N_NODES + row) * 4) = make_uint4(up[0], up[1], up[2], up[3]);
        *(uint4*)(h1b + ((size_t)(2 * w + 1) * N_NODES + row) * 4) = make_uint4(up[4], up[5], up[6], up[7]);
    }
}

// ---------------- Staged multisplit bucketize: LDS bins, aligned 16-dword flushes ----------------
__global__ __launch_bounds__(256) void k_bucketize_staged(
    const int* __restrict__ ei, int* __restrict__ gcur, unsigned* __restrict__ buf)
{
    __shared__ unsigned bin_buf[NBUCK][BCAP];   // ~75 KB
    __shared__ int bin_cnt[NBUCK];

    const int t = threadIdx.x;
    for (int i = t; i < NBUCK; i += 256) bin_cnt[i] = 0;
    __syncthreads();

    const int per = N_EDGES / SB;               // 6250 exactly
    const int e0 = blockIdx.x * per;
    const int e1 = (blockIdx.x == SB - 1) ? N_EDGES : (e0 + per);

    int cs[EPT], cd[EPT];
#pragma unroll
    for (int q = 0; q < EPT; ++q) {
        const int i = e0 + q * 256 + t;
        cs[q] = (i < e1) ? ei[i] : -1;
        cd[q] = (i < e1) ? ei[N_EDGES + i] : 0;
    }

    for (int base = e0; base < e1; base += EPR) {
        int ls[EPT], ld[EPT];
#pragma unroll
        for (int q = 0; q < EPT; ++q) { ls[q] = cs[q]; ld[q] = cd[q]; }
        const int nbase = base + EPR;
        if (nbase < e1) {
#pragma unroll
            for (int q = 0; q < EPT; ++q) {
                const int i = nbase + q * 256 + t;
                cs[q] = (i < e1) ? ei[i] : -1;
                cd[q] = (i < e1) ? ei[N_EDGES + i] : 0;
            }
        }
        // insert into LDS bins
#pragma unroll
        for (int q = 0; q < EPT; ++q) {
            if (ls[q] >= 0) {
                const int b = ld[q] >> 8;
                const int pos = atomicAdd(&bin_cnt[b], 1);
                if (pos < BCAP)
                    bin_buf[b][pos] = ((unsigned)ls[q] << 8) | (unsigned)(ld[q] & 255);
            }
        }
        __syncthreads();
        // flush full 16-groups (aligned claims -> full-line writes)
        for (int bb = t; bb < NBUCK; bb += 256) {
            const int cnt = bin_cnt[bb];
            if (cnt >= G) {
                const int take = cnt & ~(G - 1);
                const int gbase = atomicAdd(&gcur[bb * CPAD], take);
                if (gbase + take <= BUFCAP) {
                    unsigned* __restrict__ dst = buf + (size_t)bb * BUFCAP + gbase;
                    const int src0 = cnt - take;
                    for (int u = 0; u < take; u += 4) {
                        uint4 v;
                        v.x = bin_buf[bb][src0 + u];
                        v.y = bin_buf[bb][src0 + u + 1];
                        v.z = bin_buf[bb][src0 + u + 2];
                        v.w = bin_buf[bb][src0 + u + 3];
                        *(uint4*)(dst + u) = v;
                    }
                }
                bin_cnt[bb] = cnt - take;
            }
        }
        __syncthreads();
    }
    // drain partial bins
    for (int bb = t; bb < NBUCK; bb += 256) {
        const int cnt = bin_cnt[bb];
        if (cnt > 0) {
            const int gbase = atomicAdd(&gcur[bb * CPAD], cnt);
            if (gbase + cnt <= BUFCAP) {
                unsigned* __restrict__ dst = buf + (size_t)bb * BUFCAP + gbase;
                for (int u = 0; u < cnt; ++u) dst[u] = bin_buf[bb][u];
            }
        }
    }
}

// ---------------- Bucket-total scan (391 values, one block) ----------------
__global__ __launch_bounds__(512) void k_bscan(const int* __restrict__ gcur, int* __restrict__ boff)
{
    __shared__ int sm[512];
    const int t = threadIdx.x;
    const int m = (t < NBUCK) ? min(gcur[t * CPAD], BUFCAP) : 0;
    sm[t] = m;
    __syncthreads();
    for (int o = 1; o < 512; o <<= 1) {
        int a = (t >= o) ? sm[t - o] : 0;
        __syncthreads();
        sm[t] += a;
        __syncthreads();
    }
    if (t < NBUCK) boff[t] = sm[t] - m;   // exclusive
}

// ---------------- Per-bucket CSR build in LDS, dense global write ----------------
__global__ __launch_bounds__(1024) void k_csr_build(
    const int* __restrict__ gcur, const unsigned* __restrict__ buf, const int* __restrict__ boff,
    int* __restrict__ row_start, int* __restrict__ csr)
{
    __shared__ int lcsr[LCAP];      // 24 KB
    __shared__ int hist[256];
    __shared__ int lstart[257];
    __shared__ int lcur[256];

    const int b  = blockIdx.x;
    const int t  = threadIdx.x;
    const int nd = min(256, N_NODES - (b << 8));
    const int m  = min(gcur[b * CPAD], BUFCAP);
    const unsigned* __restrict__ sb = buf + (size_t)b * BUFCAP;

    if (t < 256) hist[t] = 0;
    __syncthreads();

    for (int i = t; i < m; i += 1024) atomicAdd(&hist[sb[i] & 255], 1);
    __syncthreads();

    for (int o = 1; o < 256; o <<= 1) {
        int a = 0;
        if (t < 256 && t >= o) a = hist[t - o];
        __syncthreads();
        if (t < 256) hist[t] += a;
        __syncthreads();
    }
    if (t < 256) { lstart[t + 1] = hist[t]; lcur[t] = 0; }
    if (t == 0) lstart[0] = 0;
    __syncthreads();

    for (int i = t; i < m; i += 1024) {
        const unsigned v = sb[i];
        const int dl = v & 255;
        const int p  = atomicAdd(&lcur[dl], 1);
        const int pp = lstart[dl] + p;
        if (pp < LCAP) lcsr[pp] = (int)(v >> 8);
    }
    __syncthreads();

    const int gb   = boff[b];
    const int mtot = lstart[256];
    for (int i = t; i < mtot; i += 1024) csr[gb + i] = lcsr[i];
    if (t < nd) row_start[(b << 8) + t + 1] = gb + lstart[t + 1];
    if (b == 0 && t == 0) row_start[0] = 0;
}

// ---------------- Layer-1 aggregate: XCD-bound feature slices, lane = (node, edge-phase) -------
// Block b: slice s = b&7 (blockIdx round-robins across the 8 XCDs -> slice plane, 1.6 MB, is
// L2-RESIDENT on its XCD). 256 threads = 32 node groups x 8 lanes. Lane e of node n processes
// edge slots e, e+8, ... (slot deg = implicit self edge); its uint4 IS the full 8-feature slice
// row -> no edge-data shuffles, no fast/slow path, any degree.
// No-max softmax (shift-invariant, alphas O(1..10), exp safe in fp32). den is feature-independent
// and computed identically in every slice; relu(acc/den+b1) is slice-local; the 2-wide W2 product
// is linear -> slices combine via atomicAdd into h2/as2/ad2 (zero-initialized by host memset).
__global__ __launch_bounds__(256) void k_agg1_slice(
    const int* __restrict__ row_start, const int* __restrict__ csr,
    const float* __restrict__ as1, const float* __restrict__ ad1,
    const unsigned* __restrict__ h1b,
    const float* __restrict__ b1, const float* __restrict__ W2,
    const float* __restrict__ a_s2, const float* __restrict__ a_d2,
    float* __restrict__ h2, float* __restrict__ as2, float* __restrict__ ad2)
{
    const int s  = blockIdx.x & 7;                 // feature slice == XCD (assumed b%8 mapping)
    const int nb = blockIdx.x >> 3;
    const int t  = threadIdx.x;
    const int n  = nb * 32 + (t >> 3);             // 3125*32 = 100000 exactly, no guard
    const int e  = t & 7;                          // edge phase within the 8-lane node group
    const unsigned* __restrict__ hp = h1b + (size_t)s * N_NODES * 4;

    const int r0  = row_start[n];
    const int deg = row_start[n + 1] - r0;         // real in-edges; slot 'deg' = self
    const float ad = ad1[n];

    float acc[8];
#pragma unroll
    for (int i = 0; i < 8; ++i) acc[i] = 0.f;
    float den = 0.f;

    for (int slot = e; slot <= deg; slot += 8) {
        const int sj = (slot < deg) ? csr[r0 + slot] : n;
        const uint4 u = *(const uint4*)(hp + ((size_t)sj << 2));   // L2-resident slice row
        const float p = __expf(lrelu(as1[sj] + ad));
        den += p;
        acc[0] = fmaf(p, blo(u.x), acc[0]); acc[1] = fmaf(p, bhi(u.x), acc[1]);
        acc[2] = fmaf(p, blo(u.y), acc[2]); acc[3] = fmaf(p, bhi(u.y), acc[3]);
        acc[4] = fmaf(p, blo(u.z), acc[4]); acc[5] = fmaf(p, bhi(u.z), acc[5]);
        acc[6] = fmaf(p, blo(u.w), acc[6]); acc[7] = fmaf(p, bhi(u.w), acc[7]);
    }

    // reduce across the 8-lane node group (xor 1,2,4 stays within the group)
#pragma unroll
    for (int o = 1; o <= 4; o <<= 1) {
        den += __shfl_xor(den, o, 64);
#pragma unroll
        for (int i = 0; i < 8; ++i) acc[i] += __shfl_xor(acc[i], o, 64);
    }

    // lane e owns feature f = 8s+e of this node
    const float inv = 1.f / (den + 1e-16f);
    const int f = s * 8 + e;
    float v = acc[e] * inv + b1[f];
    v = v > 0.f ? v : 0.f;
    float c0 = v * W2[2 * f + 0];
    float c1 = v * W2[2 * f + 1];
#pragma unroll
    for (int o = 1; o <= 4; o <<= 1) {
        c0 += __shfl_xor(c0, o, 64);
        c1 += __shfl_xor(c1, o, 64);
    }
    if (e == 0) {   // slice-partial contribution (linear in c0,c1)
        atomicAdd(&h2[2 * n + 0], c0);
        atomicAdd(&h2[2 * n + 1], c1);
        atomicAdd(&as2[n], c0 * a_s2[0] + c1 * a_s2[1]);
        atomicAdd(&ad2[n], c0 * a_d2[0] + c1 * a_d2[1]);
    }
}

// ---------------- Layer-2 aggregate: wave per dst, no-max softmax, parallel dual gathers --------
__global__ __launch_bounds__(256) void k_agg2_wave(
    const int* __restrict__ row_start, const int* __restrict__ csr,
    const float* __restrict__ as2, const float* __restrict__ ad2,
    const float* __restrict__ h2, const float* __restrict__ b2,
    float* __restrict__ out)
{
    const int n = blockIdx.x * 4 + (threadIdx.x >> 6);
    const int j = threadIdx.x & 63;
    if (n >= N_NODES) return;
    const int r0  = row_start[n];
    const int deg = row_start[n + 1] - r0;
    const float ad = ad2[n];
    const float2* __restrict__ h22 = (const float2*)h2;

    float den_l = 0.f, x0 = 0.f, x1 = 0.f;
    if (deg <= 63) {
        int sj = n;                                 // lanes >= deg: self row
        if (j < deg) sj = csr[r0 + j];
        const float  aj = as2[sj];                  // both gathers in flight together
        const float2 hv = h22[sj];
        float p = 0.f;
        if (j <= deg) p = __expf(lrelu(aj + ad));
        den_l = p; x0 = p * hv.x; x1 = p * hv.y;
    } else {
        if (j == 0) {   // self edge
            const float p = __expf(lrelu(as2[n] + ad));
            const float2 hv = h22[n];
            den_l = p; x0 = p * hv.x; x1 = p * hv.y;
        }
        for (int idx = r0 + j; idx < r0 + deg; idx += 64) {
            const int s = csr[idx];
            const float p = __expf(lrelu(as2[s] + ad));
            const float2 hv = h22[s];
            den_l += p; x0 = fmaf(p, hv.x, x0); x1 = fmaf(p, hv.y, x1);
        }
    }
#pragma unroll
    for (int o = 32; o; o >>= 1) {
        den_l += __shfl_xor(den_l, o, 64);
        x0    += __shfl_xor(x0, o, 64);
        x1    += __shfl_xor(x1, o, 64);
    }
    if (j == 0) {
        const float inv = 1.f / (den_l + 1e-16f);
        out[n * 2 + 0] = x0 * inv + b2[0];
        out[n * 2 + 1] = x1 * inv + b2[1];
    }
}

extern "C" void kernel_launch(void* const* d_in, const int* in_sizes, int n_in,
                              void* d_out, int out_size, void* d_ws, size_t ws_size,
                              hipStream_t stream)
{
    const float* x    = (const float*)d_in[0];
    const int*   ei   = (const int*)d_in[1];
    const float* W1   = (const float*)d_in[2];
    const float* as1w = (const float*)d_in[3];
    const float* ad1w = (const float*)d_in[4];
    const float* b1   = (const float*)d_in[5];
    const float* W2   = (const float*)d_in[6];
    const float* as2w = (const float*)d_in[7];
    const float* ad2w = (const float*)d_in[8];
    const float* b2   = (const float*)d_in[9];
    float* out = (float*)d_out;

    float* ws = (float*)d_ws;
    size_t off = 0;
    unsigned* h1b = (unsigned*)(ws + off); off += (size_t)N_NODES * 32;  // 12.8 MB, slice-planar
    float* as1 = ws + off; off += N_NODES;
    float* ad1 = ws + off; off += N_NODES;
    float* h2  = ws + off; off += (size_t)N_NODES * 2;   // h2, as2, ad2 contiguous (one memset)
    float* as2 = ws + off; off += N_NODES;
    float* ad2 = ws + off; off += N_NODES;
    int* gcur      = (int*)(ws + off); off += NBUCK * CPAD;              // 25 KB, zeroed
    unsigned* buf  = (unsigned*)(ws + off); off += (size_t)NBUCK * BUFCAP;  // 9.6 MB
    int* boff      = (int*)(ws + off); off += NBUCK + 1;
    int* row_start = (int*)(ws + off); off += N_NODES + 1;
    int* csr       = (int*)(ws + off); off += N_EDGES;

    hipMemsetAsync(gcur, 0, NBUCK * CPAD * sizeof(int), stream);
    hipMemsetAsync(h2, 0, (size_t)N_NODES * 4 * sizeof(float), stream);  // h2+as2+ad2 accumulators

    k_gemm1           <<<(N_NODES + 63) / 64, 256, 0, stream>>>(x, W1, as1w, ad1w, h1b, as1, ad1);
    k_bucketize_staged<<<SB, 256, 0, stream>>>(ei, gcur, buf);
    k_bscan           <<<1, 512, 0, stream>>>(gcur, boff);
    k_csr_build       <<<NBUCK, 1024, 0, stream>>>(gcur, buf, boff, row_start, csr);
    k_agg1_slice      <<<(N_NODES / 32) * 8, 256, 0, stream>>>(
        row_start, csr, as1, ad1, h1b, b1, W2, as2w, ad2w, h2, as2, ad2);
    k_agg2_wave       <<<(N_NODES + 3) / 4, 256, 0, stream>>>(row_start, csr, as2, ad2, h2, b2, out);
}

// Round 12
// 245.930 us; speedup vs baseline: 1.2826x; 1.2826x over previous
//
#include <hip/hip_runtime.h>
#include <math.h>

constexpr int N_NODES = 100000;
constexpr int N_EDGES = 1600000;
constexpr int F_IN    = 128;
constexpr int F_H     = 64;
constexpr float NEG_SLOPE = 0.2f;

constexpr int NBUCK  = (N_NODES + 255) / 256;  // 391 buckets of 256 dst nodes
constexpr int BUFCAP = 6144;                   // per-bucket stream cap (mean 4092, +32 sigma)
constexpr int LCAP   = 6144;
constexpr int CPAD   = 16;                     // gcur stride in ints: one 64B line per counter

// staged multisplit params
constexpr int SB   = 256;                      // staging blocks (75KB LDS -> 2 blocks/CU, all CUs)
constexpr int EPT  = 4;                        // edges per thread per round
constexpr int EPR  = 256 * EPT;                // 1024 edges per round
constexpr int G    = 16;                       // flush granularity = one 64B line
constexpr int BCAP = 48;                       // LDS bin capacity (15 carry + Poisson(2.62) tail)

__device__ inline float lrelu(float v) { return v > 0.f ? v : NEG_SLOPE * v; }
// bf16-pair unpack: u32 holds [lo = feature 2i, hi = feature 2i+1]
__device__ inline float blo(unsigned u) { return __uint_as_float(u << 16); }
__device__ inline float bhi(unsigned u) { return __uint_as_float(u & 0xFFFF0000u); }
// RNE float->bf16 (as high 16 bits)
__device__ inline unsigned bf16hi(float f) {
    unsigned u = __float_as_uint(f);
    return (u + 0x7FFFu + ((u >> 16) & 1u)) & 0xFFFF0000u;
}
__device__ inline unsigned bf16lo(float f) {
    unsigned u = __float_as_uint(f);
    return (u + 0x7FFFu + ((u >> 16) & 1u)) >> 16;
}

// ---------------- GEMM: block = 64 rows, 4 waves split the 64 features (16 each) ----------------
// h1b NODE-MAJOR (R8 layout): row = 32 u32 = 128B of bf16 pairs.
// 1-deep software pipeline on the x row: xr[k4+1] issued before k4's FMAs, so the streamed
// load has a full iteration of FMA issue (~128cy) plus scheduling slack to land.
__global__ __launch_bounds__(256) void k_gemm1(
    const float* __restrict__ x, const float* __restrict__ W1,
    const float* __restrict__ a_s, const float* __restrict__ a_d,
    unsigned* __restrict__ h1b, float* __restrict__ as1, float* __restrict__ ad1)
{
    __shared__ float vsP[4][64];
    __shared__ float vdP[4][64];

    const int lane = threadIdx.x & 63;
    const int w    = __builtin_amdgcn_readfirstlane(threadIdx.x >> 6);  // SGPR wave id
    const int fo   = w * 16;                 // feature offset (wave-uniform)
    const int row  = blockIdx.x * 64 + lane;
    const bool valid = row < N_NODES;

    float acc[16];
#pragma unroll
    for (int i = 0; i < 16; ++i) acc[i] = 0.f;

    if (valid) {
        const float4* __restrict__ xr = (const float4*)(x + (size_t)row * F_IN);
        float4 xv = xr[0];
        for (int k4 = 0; k4 < F_IN / 4; ++k4) {
            const float4 xn = xr[(k4 + 1) & (F_IN / 4 - 1)];   // prefetch (wraps harmlessly)
            const float* __restrict__ wk = W1 + (size_t)k4 * 4 * F_H + fo;  // wave-uniform
#pragma unroll
            for (int kk = 0; kk < 4; ++kk) {
                const float xs = (kk == 0) ? xv.x : (kk == 1) ? xv.y : (kk == 2) ? xv.z : xv.w;
                const float* __restrict__ ws = wk + kk * F_H;   // scalar loads (SGPR base)
#pragma unroll
                for (int i = 0; i < 16; ++i)
                    acc[i] = fmaf(xs, ws[i], acc[i]);
            }
            xv = xn;
        }
    }

    // partial alphas over this wave's 16 features (fp32, pre-rounding)
    float vs = 0.f, vd = 0.f;
#pragma unroll
    for (int i = 0; i < 16; ++i) {
        vs = fmaf(acc[i], a_s[fo + i], vs);
        vd = fmaf(acc[i], a_d[fo + i], vd);
    }
    vsP[w][lane] = vs;
    vdP[w][lane] = vd;
    __syncthreads();
    if (w == 0 && valid) {
        as1[row] = vsP[0][lane] + vsP[1][lane] + vsP[2][lane] + vsP[3][lane];
        ad1[row] = vdP[0][lane] + vdP[1][lane] + vdP[2][lane] + vdP[3][lane];
    }

    if (valid) {
        // pack this wave's 16 features -> 8 u32 (bf16 RNE), write slice [8w, 8w+8)
        unsigned up[8];
#pragma unroll
        for (int i = 0; i < 8; ++i)
            up[i] = bf16lo(acc[2 * i]) | bf16hi(acc[2 * i + 1]);
        uint4* __restrict__ hr = (uint4*)(h1b + (size_t)row * 32 + w * 8);
        hr[0] = make_uint4(up[0], up[1], up[2], up[3]);
        hr[1] = make_uint4(up[4], up[5], up[6], up[7]);
    }
}

// ---------------- Staged multisplit bucketize: LDS bins, aligned 16-dword flushes ----------------
__global__ __launch_bounds__(256) void k_bucketize_staged(
    const int* __restrict__ ei, int* __restrict__ gcur, unsigned* __restrict__ buf)
{
    __shared__ unsigned bin_buf[NBUCK][BCAP];   // ~75 KB
    __shared__ int bin_cnt[NBUCK];

    const int t = threadIdx.x;
    for (int i = t; i < NBUCK; i += 256) bin_cnt[i] = 0;
    __syncthreads();

    const int per = N_EDGES / SB;               // 6250 exactly
    const int e0 = blockIdx.x * per;
    const int e1 = (blockIdx.x == SB - 1) ? N_EDGES : (e0 + per);

    int cs[EPT], cd[EPT];
#pragma unroll
    for (int q = 0; q < EPT; ++q) {
        const int i = e0 + q * 256 + t;
        cs[q] = (i < e1) ? ei[i] : -1;
        cd[q] = (i < e1) ? ei[N_EDGES + i] : 0;
    }

    for (int base = e0; base < e1; base += EPR) {
        int ls[EPT], ld[EPT];
#pragma unroll
        for (int q = 0; q < EPT; ++q) { ls[q] = cs[q]; ld[q] = cd[q]; }
        const int nbase = base + EPR;
        if (nbase < e1) {
#pragma unroll
            for (int q = 0; q < EPT; ++q) {
                const int i = nbase + q * 256 + t;
                cs[q] = (i < e1) ? ei[i] : -1;
                cd[q] = (i < e1) ? ei[N_EDGES + i] : 0;
            }
        }
        // insert into LDS bins
#pragma unroll
        for (int q = 0; q < EPT; ++q) {
            if (ls[q] >= 0) {
                const int b = ld[q] >> 8;
                const int pos = atomicAdd(&bin_cnt[b], 1);
                if (pos < BCAP)
                    bin_buf[b][pos] = ((unsigned)ls[q] << 8) | (unsigned)(ld[q] & 255);
            }
        }
        __syncthreads();
        // flush full 16-groups (aligned claims -> full-line writes)
        for (int bb = t; bb < NBUCK; bb += 256) {
            const int cnt = bin_cnt[bb];
            if (cnt >= G) {
                const int take = cnt & ~(G - 1);
                const int gbase = atomicAdd(&gcur[bb * CPAD], take);
                if (gbase + take <= BUFCAP) {
                    unsigned* __restrict__ dst = buf + (size_t)bb * BUFCAP + gbase;
                    const int src0 = cnt - take;
                    for (int u = 0; u < take; u += 4) {
                        uint4 v;
                        v.x = bin_buf[bb][src0 + u];
                        v.y = bin_buf[bb][src0 + u + 1];
                        v.z = bin_buf[bb][src0 + u + 2];
                        v.w = bin_buf[bb][src0 + u + 3];
                        *(uint4*)(dst + u) = v;
                    }
                }
                bin_cnt[bb] = cnt - take;
            }
        }
        __syncthreads();
    }
    // drain partial bins
    for (int bb = t; bb < NBUCK; bb += 256) {
        const int cnt = bin_cnt[bb];
        if (cnt > 0) {
            const int gbase = atomicAdd(&gcur[bb * CPAD], cnt);
            if (gbase + cnt <= BUFCAP) {
                unsigned* __restrict__ dst = buf + (size_t)bb * BUFCAP + gbase;
                for (int u = 0; u < cnt; ++u) dst[u] = bin_buf[bb][u];
            }
        }
    }
}

// ---------------- Bucket-total scan (391 values, one block) ----------------
__global__ __launch_bounds__(512) void k_bscan(const int* __restrict__ gcur, int* __restrict__ boff)
{
    __shared__ int sm[512];
    const int t = threadIdx.x;
    const int m = (t < NBUCK) ? min(gcur[t * CPAD], BUFCAP) : 0;
    sm[t] = m;
    __syncthreads();
    for (int o = 1; o < 512; o <<= 1) {
        int a = (t >= o) ? sm[t - o] : 0;
        __syncthreads();
        sm[t] += a;
        __syncthreads();
    }
    if (t < NBUCK) boff[t] = sm[t] - m;   // exclusive
}

// ---------------- Per-bucket CSR build in LDS, dense global write ----------------
__global__ __launch_bounds__(1024) void k_csr_build(
    const int* __restrict__ gcur, const unsigned* __restrict__ buf, const int* __restrict__ boff,
    int* __restrict__ row_start, int* __restrict__ csr)
{
    __shared__ int lcsr[LCAP];      // 24 KB
    __shared__ int hist[256];
    __shared__ int lstart[257];
    __shared__ int lcur[256];

    const int b  = blockIdx.x;
    const int t  = threadIdx.x;
    const int nd = min(256, N_NODES - (b << 8));
    const int m  = min(gcur[b * CPAD], BUFCAP);
    const unsigned* __restrict__ sb = buf + (size_t)b * BUFCAP;

    if (t < 256) hist[t] = 0;
    __syncthreads();

    for (int i = t; i < m; i += 1024) atomicAdd(&hist[sb[i] & 255], 1);
    __syncthreads();

    for (int o = 1; o < 256; o <<= 1) {
        int a = 0;
        if (t < 256 && t >= o) a = hist[t - o];
        __syncthreads();
        if (t < 256) hist[t] += a;
        __syncthreads();
    }
    if (t < 256) { lstart[t + 1] = hist[t]; lcur[t] = 0; }
    if (t == 0) lstart[0] = 0;
    __syncthreads();

    for (int i = t; i < m; i += 1024) {
        const unsigned v = sb[i];
        const int dl = v & 255;
        const int p  = atomicAdd(&lcur[dl], 1);
        const int pp = lstart[dl] + p;
        if (pp < LCAP) lcsr[pp] = (int)(v >> 8);
    }
    __syncthreads();

    const int gb   = boff[b];
    const int mtot = lstart[256];
    for (int i = t; i < mtot; i += 1024) csr[gb + i] = lcsr[i];
    if (t < nd) row_start[(b << 8) + t + 1] = gb + lstart[t + 1];
    if (b == 0 && t == 0) row_start[0] = 0;
}

// ---------------- Layer-1 aggregate: wave per dst, no-max softmax (R8-proven version) ----------
// Lane l: group g = l>>3 covers features 8*(l&7)..+7 (one uint4 = 8 bf16). Slots 0..31 are
// UNCONDITIONAL: pad slots carry sj=n -> re-load row n (L1-hit, no extra HBM), pj=0.
// No-max softmax (shift-invariant; alphas O(1..10) by init scaling, exp safe in fp32).
__global__ __launch_bounds__(256) void k_agg1(
    const int* __restrict__ row_start, const int* __restrict__ csr,
    const float* __restrict__ as1, const float* __restrict__ ad1,
    const unsigned* __restrict__ h1b,
    const float* __restrict__ b1, const float* __restrict__ W2,
    const float* __restrict__ a_s2, const float* __restrict__ a_d2,
    float* __restrict__ h2, float* __restrict__ as2, float* __restrict__ ad2)
{
    const int n = blockIdx.x * 4 + (threadIdx.x >> 6);
    const int j = threadIdx.x & 63;
    if (n >= N_NODES) return;

    const int g  = j >> 3;        // edge-phase group 0..7
    const int oq = (j & 7) << 2;  // u32 offset in row (4 u32 = 8 features)

    const int r0  = row_start[n];
    const int deg = row_start[n + 1] - r0;   // real in-edges; +1 implicit self
    const float ad = ad1[n];

    float acc0[8], acc1[8];
#pragma unroll
    for (int i = 0; i < 8; ++i) { acc0[i] = 0.f; acc1[i] = 0.f; }
    float den_l = 0.f;

#define FMA8(ACC, P, U)                                            \
    ACC[0] = fmaf(P, blo(U.x), ACC[0]); ACC[1] = fmaf(P, bhi(U.x), ACC[1]); \
    ACC[2] = fmaf(P, blo(U.y), ACC[2]); ACC[3] = fmaf(P, bhi(U.y), ACC[3]); \
    ACC[4] = fmaf(P, blo(U.z), ACC[4]); ACC[5] = fmaf(P, bhi(U.z), ACC[5]); \
    ACC[6] = fmaf(P, blo(U.w), ACC[6]); ACC[7] = fmaf(P, bhi(U.w), ACC[7]);
#define LD8(S) (*(const uint4*)(h1b + ((size_t)(S) << 5) + oq))

    if (deg <= 63) {               // fast path: edges + self in one wave chunk
        int sj = n;                // lanes >= deg: self row (lane 'deg' IS the self edge)
        if (j < deg) sj = csr[r0 + j];
        const float aj = as1[sj];                 // gather, issued first (valid for pads too)
        // slot shuffles + gather issues, independent of alphas
        const int s0 = __shfl(sj, g,      64);
        const int s1 = __shfl(sj, 8 + g,  64);
        const int s2 = __shfl(sj, 16 + g, 64);
        const int s3 = __shfl(sj, 24 + g, 64);
        const uint4 u0 = LD8(s0);
        const uint4 u1 = LD8(s1);
        const uint4 u2 = LD8(s2);
        const uint4 u3 = LD8(s3);
        // p while gathers are in flight (waits only on aj)
        float pj = 0.f;
        if (j <= deg) pj = __expf(lrelu(aj + ad));
        den_l = pj;
        const float p0 = __shfl(pj, g,      64);
        const float p1 = __shfl(pj, 8 + g,  64);
        const float p2 = __shfl(pj, 16 + g, 64);
        const float p3 = __shfl(pj, 24 + g, 64);
        FMA8(acc0, p0, u0) FMA8(acc1, p1, u1)
        FMA8(acc0, p2, u2) FMA8(acc1, p3, u3)

        const int tot = deg + 1;
        if (tot > 32) {            // rare (~3e-4 of nodes), wave-uniform guard
            const int s4 = __shfl(sj, 32 + g, 64);
            const int s5 = __shfl(sj, 40 + g, 64);
            const int s6 = __shfl(sj, 48 + g, 64);
            const int s7 = __shfl(sj, 56 + g, 64);
            const uint4 u4 = LD8(s4);
            const uint4 u5 = LD8(s5);
            const uint4 u6 = LD8(s6);
            const uint4 u7 = LD8(s7);
            const float p4 = __shfl(pj, 32 + g, 64);
            const float p5 = __shfl(pj, 40 + g, 64);
            const float p6 = __shfl(pj, 48 + g, 64);
            const float p7 = __shfl(pj, 56 + g, 64);
            FMA8(acc0, p4, u4) FMA8(acc1, p5, u5)
            FMA8(acc0, p6, u6) FMA8(acc1, p7, u7)
        }
    } else {                       // generic chunked path + explicit self (stat. never taken)
        {   // self edge: group 0 lanes cover all 8 feature-octs
            const float ps = __expf(lrelu(as1[n] + ad));
            if (j == 0) den_l += ps;
            if (g == 0) {
                const uint4 uv = LD8(n);
                FMA8(acc0, ps, uv)
            }
        }
        for (int cb = r0; cb < r0 + deg; cb += 64) {
            const int cnt = min(64, r0 + deg - cb);   // wave-uniform
            int sj = 0; float pj = 0.f;               // pad lanes: valid row 0, p = 0
            if (j < cnt) { sj = csr[cb + j]; pj = __expf(lrelu(as1[sj] + ad)); }
            den_l += pj;
            for (int base = 0; base < cnt; base += 16) {
                const int   sA = __shfl(sj, base + g, 64);
                const float pA = __shfl(pj, base + g, 64);
                const uint4 ua = LD8(sA);
                FMA8(acc0, pA, ua)
                if (base + 8 < cnt) {
                    const int   sB = __shfl(sj, base + 8 + g, 64);
                    const float pB = __shfl(pj, base + 8 + g, 64);
                    const uint4 ub = LD8(sB);
                    FMA8(acc1, pB, ub)
                }
            }
        }
    }
#undef FMA8
#undef LD8

    float den = den_l;
#pragma unroll
    for (int o = 32; o; o >>= 1) den += __shfl_xor(den, o, 64);

    // merge unroll chains, then sum the 8 edge-groups (lanes with equal j&7)
#pragma unroll
    for (int i = 0; i < 8; ++i) acc0[i] += acc1[i];
#pragma unroll
    for (int o = 8; o <= 32; o <<= 1) {
#pragma unroll
        for (int i = 0; i < 8; ++i) acc0[i] += __shfl_xor(acc0[i], o, 64);
    }

    // layer-1 epilogue + 64x2 layer-2 GEMM + alpha2 (features ob..ob+7 per lane)
    const float inv = 1.f / (den + 1e-16f);
    const int ob = (j & 7) << 3;
    const float4 b0 = *(const float4*)(b1 + ob);
    const float4 b4 = *(const float4*)(b1 + ob + 4);
    float v[8];
    v[0] = acc0[0] * inv + b0.x; v[1] = acc0[1] * inv + b0.y;
    v[2] = acc0[2] * inv + b0.z; v[3] = acc0[3] * inv + b0.w;
    v[4] = acc0[4] * inv + b4.x; v[5] = acc0[5] * inv + b4.y;
    v[6] = acc0[6] * inv + b4.z; v[7] = acc0[7] * inv + b4.w;
#pragma unroll
    for (int i = 0; i < 8; ++i) v[i] = v[i] > 0.f ? v[i] : 0.f;

    const float4* __restrict__ wq = (const float4*)(W2 + 2 * ob);  // rows ob..ob+7, 2 cols
    const float4 w0 = wq[0], w1 = wq[1], w2 = wq[2], w3 = wq[3];
    float c0 = v[0] * w0.x + v[1] * w0.z + v[2] * w1.x + v[3] * w1.z
             + v[4] * w2.x + v[5] * w2.z + v[6] * w3.x + v[7] * w3.z;
    float c1 = v[0] * w0.y + v[1] * w0.w + v[2] * w1.y + v[3] * w1.w
             + v[4] * w2.y + v[5] * w2.w + v[6] * w3.y + v[7] * w3.w;
#pragma unroll
    for (int o = 1; o <= 4; o <<= 1) {   // sum the 8 feature-octs within the group
        c0 += __shfl_xor(c0, o, 64);
        c1 += __shfl_xor(c1, o, 64);
    }
    if (j == 0) {
        h2[n * 2 + 0] = c0;
        h2[n * 2 + 1] = c1;
        as2[n] = c0 * a_s2[0] + c1 * a_s2[1];
        ad2[n] = c0 * a_d2[0] + c1 * a_d2[1];
    }
}

// ---------------- Layer-2 aggregate: wave per dst, no-max softmax, parallel dual gathers --------
__global__ __launch_bounds__(256) void k_agg2_wave(
    const int* __restrict__ row_start, const int* __restrict__ csr,
    const float* __restrict__ as2, const float* __restrict__ ad2,
    const float* __restrict__ h2, const float* __restrict__ b2,
    float* __restrict__ out)
{
    const int n = blockIdx.x * 4 + (threadIdx.x >> 6);
    const int j = threadIdx.x & 63;
    if (n >= N_NODES) return;
    const int r0  = row_start[n];
    const int deg = row_start[n + 1] - r0;
    const float ad = ad2[n];
    const float2* __restrict__ h22 = (const float2*)h2;

    float den_l = 0.f, x0 = 0.f, x1 = 0.f;
    if (deg <= 63) {
        int sj = n;                                 // lanes >= deg: self row
        if (j < deg) sj = csr[r0 + j];
        const float  aj = as2[sj];                  // both gathers in flight together
        const float2 hv = h22[sj];
        float p = 0.f;
        if (j <= deg) p = __expf(lrelu(aj + ad));
        den_l = p; x0 = p * hv.x; x1 = p * hv.y;
    } else {
        if (j == 0) {   // self edge
            const float p = __expf(lrelu(as2[n] + ad));
            const float2 hv = h22[n];
            den_l = p; x0 = p * hv.x; x1 = p * hv.y;
        }
        for (int idx = r0 + j; idx < r0 + deg; idx += 64) {
            const int s = csr[idx];
            const float p = __expf(lrelu(as2[s] + ad));
            const float2 hv = h22[s];
            den_l += p; x0 = fmaf(p, hv.x, x0); x1 = fmaf(p, hv.y, x1);
        }
    }
#pragma unroll
    for (int o = 32; o; o >>= 1) {
        den_l += __shfl_xor(den_l, o, 64);
        x0    += __shfl_xor(x0, o, 64);
        x1    += __shfl_xor(x1, o, 64);
    }
    if (j == 0) {
        const float inv = 1.f / (den_l + 1e-16f);
        out[n * 2 + 0] = x0 * inv + b2[0];
        out[n * 2 + 1] = x1 * inv + b2[1];
    }
}

extern "C" void kernel_launch(void* const* d_in, const int* in_sizes, int n_in,
                              void* d_out, int out_size, void* d_ws, size_t ws_size,
                              hipStream_t stream)
{
    const float* x    = (const float*)d_in[0];
    const int*   ei   = (const int*)d_in[1];
    const float* W1   = (const float*)d_in[2];
    const float* as1w = (const float*)d_in[3];
    const float* ad1w = (const float*)d_in[4];
    const float* b1   = (const float*)d_in[5];
    const float* W2   = (const float*)d_in[6];
    const float* as2w = (const float*)d_in[7];
    const float* ad2w = (const float*)d_in[8];
    const float* b2   = (const float*)d_in[9];
    float* out = (float*)d_out;

    float* ws = (float*)d_ws;
    size_t off = 0;
    unsigned* h1b = (unsigned*)(ws + off); off += (size_t)N_NODES * 32;  // 12.8 MB, node-major
    float* as1 = ws + off; off += N_NODES;
    float* ad1 = ws + off; off += N_NODES;
    float* h2  = ws + off; off += (size_t)N_NODES * 2;
    float* as2 = ws + off; off += N_NODES;
    float* ad2 = ws + off; off += N_NODES;
    int* gcur      = (int*)(ws + off); off += NBUCK * CPAD;              // 25 KB, zeroed
    unsigned* buf  = (unsigned*)(ws + off); off += (size_t)NBUCK * BUFCAP;  // 9.6 MB
    int* boff      = (int*)(ws + off); off += NBUCK + 1;
    int* row_start = (int*)(ws + off); off += N_NODES + 1;
    int* csr       = (int*)(ws + off); off += N_EDGES;

    hipMemsetAsync(gcur, 0, NBUCK * CPAD * sizeof(int), stream);

    k_gemm1           <<<(N_NODES + 63) / 64, 256, 0, stream>>>(x, W1, as1w, ad1w, h1b, as1, ad1);
    k_bucketize_staged<<<SB, 256, 0, stream>>>(ei, gcur, buf);
    k_bscan           <<<1, 512, 0, stream>>>(gcur, boff);
    k_csr_build       <<<NBUCK, 1024, 0, stream>>>(gcur, buf, boff, row_start, csr);
    k_agg1            <<<(N_NODES + 3) / 4, 256, 0, stream>>>(
        row_start, csr, as1, ad1, h1b, b1, W2, as2w, ad2w, h2, as2, ad2);
    k_agg2_wave       <<<(N_NODES + 3) / 4, 256, 0, stream>>>(row_start, csr, as2, ad2, h2, b2, out);
}

// Round 13
// 245.434 us; speedup vs baseline: 1.2852x; 1.0020x over previous
//
#include <hip/hip_runtime.h>
#include <math.h>

constexpr int N_NODES = 100000;
constexpr int N_EDGES = 1600000;
constexpr int F_IN    = 128;
constexpr int F_H     = 64;
constexpr float NEG_SLOPE = 0.2f;

constexpr int NBUCK  = (N_NODES + 255) / 256;  // 391 buckets of 256 dst nodes
constexpr int BUFCAP = 6144;                   // per-bucket stream cap (mean 4092, +32 sigma)
constexpr int LCAP   = 6144;
constexpr int CPAD   = 16;                     // gcur stride in ints: one 64B line per counter

// staged multisplit params
constexpr int SB   = 256;                      // staging blocks (75KB LDS -> 2 blocks/CU, all CUs)
constexpr int EPT  = 4;                        // edges per thread per round
constexpr int EPR  = 256 * EPT;                // 1024 edges per round
constexpr int G    = 16;                       // flush granularity = one 64B line
constexpr int BCAP = 48;                       // LDS bin capacity (15 carry + Poisson(2.62) tail)

__device__ inline float lrelu(float v) { return v > 0.f ? v : NEG_SLOPE * v; }
// bf16-pair unpack: u32 holds [lo = feature 2i, hi = feature 2i+1]
__device__ inline float blo(unsigned u) { return __uint_as_float(u << 16); }
__device__ inline float bhi(unsigned u) { return __uint_as_float(u & 0xFFFF0000u); }
// RNE float->bf16 (as high 16 bits)
__device__ inline unsigned bf16hi(float f) {
    unsigned u = __float_as_uint(f);
    return (u + 0x7FFFu + ((u >> 16) & 1u)) & 0xFFFF0000u;
}
__device__ inline unsigned bf16lo(float f) {
    unsigned u = __float_as_uint(f);
    return (u + 0x7FFFu + ((u >> 16) & 1u)) >> 16;
}

// ---------------- GEMM: block = 64 rows, 4 waves split the 64 features (16 each) ----------------
// h1b NODE-MAJOR (R8 layout): row = 32 u32 = 128B of bf16 pairs.
__global__ __launch_bounds__(256) void k_gemm1(
    const float* __restrict__ x, const float* __restrict__ W1,
    const float* __restrict__ a_s, const float* __restrict__ a_d,
    unsigned* __restrict__ h1b, float* __restrict__ as1, float* __restrict__ ad1)
{
    __shared__ float vsP[4][64];
    __shared__ float vdP[4][64];

    const int lane = threadIdx.x & 63;
    const int w    = __builtin_amdgcn_readfirstlane(threadIdx.x >> 6);  // SGPR wave id
    const int fo   = w * 16;                 // feature offset (wave-uniform)
    const int row  = blockIdx.x * 64 + lane;
    const bool valid = row < N_NODES;

    float acc[16];
#pragma unroll
    for (int i = 0; i < 16; ++i) acc[i] = 0.f;

    if (valid) {
        const float4* __restrict__ xr = (const float4*)(x + (size_t)row * F_IN);
        float4 xv = xr[0];
        for (int k4 = 0; k4 < F_IN / 4; ++k4) {
            const float4 xn = xr[(k4 + 1) & (F_IN / 4 - 1)];   // prefetch (wraps harmlessly)
            const float* __restrict__ wk = W1 + (size_t)k4 * 4 * F_H + fo;  // wave-uniform
#pragma unroll
            for (int kk = 0; kk < 4; ++kk) {
                const float xs = (kk == 0) ? xv.x : (kk == 1) ? xv.y : (kk == 2) ? xv.z : xv.w;
                const float* __restrict__ ws = wk + kk * F_H;   // scalar loads (SGPR base)
#pragma unroll
                for (int i = 0; i < 16; ++i)
                    acc[i] = fmaf(xs, ws[i], acc[i]);
            }
            xv = xn;
        }
    }

    // partial alphas over this wave's 16 features (fp32, pre-rounding)
    float vs = 0.f, vd = 0.f;
#pragma unroll
    for (int i = 0; i < 16; ++i) {
        vs = fmaf(acc[i], a_s[fo + i], vs);
        vd = fmaf(acc[i], a_d[fo + i], vd);
    }
    vsP[w][lane] = vs;
    vdP[w][lane] = vd;
    __syncthreads();
    if (w == 0 && valid) {
        as1[row] = vsP[0][lane] + vsP[1][lane] + vsP[2][lane] + vsP[3][lane];
        ad1[row] = vdP[0][lane] + vdP[1][lane] + vdP[2][lane] + vdP[3][lane];
    }

    if (valid) {
        // pack this wave's 16 features -> 8 u32 (bf16 RNE), write slice [8w, 8w+8)
        unsigned up[8];
#pragma unroll
        for (int i = 0; i < 8; ++i)
            up[i] = bf16lo(acc[2 * i]) | bf16hi(acc[2 * i + 1]);
        uint4* __restrict__ hr = (uint4*)(h1b + (size_t)row * 32 + w * 8);
        hr[0] = make_uint4(up[0], up[1], up[2], up[3]);
        hr[1] = make_uint4(up[4], up[5], up[6], up[7]);
    }
}

// ---------------- Staged multisplit bucketize: LDS bins, aligned 16-dword flushes ----------------
__global__ __launch_bounds__(256) void k_bucketize_staged(
    const int* __restrict__ ei, int* __restrict__ gcur, unsigned* __restrict__ buf)
{
    __shared__ unsigned bin_buf[NBUCK][BCAP];   // ~75 KB
    __shared__ int bin_cnt[NBUCK];

    const int t = threadIdx.x;
    for (int i = t; i < NBUCK; i += 256) bin_cnt[i] = 0;
    __syncthreads();

    const int per = N_EDGES / SB;               // 6250 exactly
    const int e0 = blockIdx.x * per;
    const int e1 = (blockIdx.x == SB - 1) ? N_EDGES : (e0 + per);

    int cs[EPT], cd[EPT];
#pragma unroll
    for (int q = 0; q < EPT; ++q) {
        const int i = e0 + q * 256 + t;
        cs[q] = (i < e1) ? ei[i] : -1;
        cd[q] = (i < e1) ? ei[N_EDGES + i] : 0;
    }

    for (int base = e0; base < e1; base += EPR) {
        int ls[EPT], ld[EPT];
#pragma unroll
        for (int q = 0; q < EPT; ++q) { ls[q] = cs[q]; ld[q] = cd[q]; }
        const int nbase = base + EPR;
        if (nbase < e1) {
#pragma unroll
            for (int q = 0; q < EPT; ++q) {
                const int i = nbase + q * 256 + t;
                cs[q] = (i < e1) ? ei[i] : -1;
                cd[q] = (i < e1) ? ei[N_EDGES + i] : 0;
            }
        }
        // insert into LDS bins
#pragma unroll
        for (int q = 0; q < EPT; ++q) {
            if (ls[q] >= 0) {
                const int b = ld[q] >> 8;
                const int pos = atomicAdd(&bin_cnt[b], 1);
                if (pos < BCAP)
                    bin_buf[b][pos] = ((unsigned)ls[q] << 8) | (unsigned)(ld[q] & 255);
            }
        }
        __syncthreads();
        // flush full 16-groups (aligned claims -> full-line writes)
        for (int bb = t; bb < NBUCK; bb += 256) {
            const int cnt = bin_cnt[bb];
            if (cnt >= G) {
                const int take = cnt & ~(G - 1);
                const int gbase = atomicAdd(&gcur[bb * CPAD], take);
                if (gbase + take <= BUFCAP) {
                    unsigned* __restrict__ dst = buf + (size_t)bb * BUFCAP + gbase;
                    const int src0 = cnt - take;
                    for (int u = 0; u < take; u += 4) {
                        uint4 v;
                        v.x = bin_buf[bb][src0 + u];
                        v.y = bin_buf[bb][src0 + u + 1];
                        v.z = bin_buf[bb][src0 + u + 2];
                        v.w = bin_buf[bb][src0 + u + 3];
                        *(uint4*)(dst + u) = v;
                    }
                }
                bin_cnt[bb] = cnt - take;
            }
        }
        __syncthreads();
    }
    // drain partial bins
    for (int bb = t; bb < NBUCK; bb += 256) {
        const int cnt = bin_cnt[bb];
        if (cnt > 0) {
            const int gbase = atomicAdd(&gcur[bb * CPAD], cnt);
            if (gbase + cnt <= BUFCAP) {
                unsigned* __restrict__ dst = buf + (size_t)bb * BUFCAP + gbase;
                for (int u = 0; u < cnt; ++u) dst[u] = bin_buf[bb][u];
            }
        }
    }
}

// ---------------- Bucket-total scan (391 values, one block) ----------------
__global__ __launch_bounds__(512) void k_bscan(const int* __restrict__ gcur, int* __restrict__ boff)
{
    __shared__ int sm[512];
    const int t = threadIdx.x;
    const int m = (t < NBUCK) ? min(gcur[t * CPAD], BUFCAP) : 0;
    sm[t] = m;
    __syncthreads();
    for (int o = 1; o < 512; o <<= 1) {
        int a = (t >= o) ? sm[t - o] : 0;
        __syncthreads();
        sm[t] += a;
        __syncthreads();
    }
    if (t < NBUCK) boff[t] = sm[t] - m;   // exclusive
}

// ---------------- Per-bucket CSR build in LDS, dense global write ----------------
__global__ __launch_bounds__(1024) void k_csr_build(
    const int* __restrict__ gcur, const unsigned* __restrict__ buf, const int* __restrict__ boff,
    int* __restrict__ row_start, int* __restrict__ csr)
{
    __shared__ int lcsr[LCAP];      // 24 KB
    __shared__ int hist[256];
    __shared__ int lstart[257];
    __shared__ int lcur[256];

    const int b  = blockIdx.x;
    const int t  = threadIdx.x;
    const int nd = min(256, N_NODES - (b << 8));
    const int m  = min(gcur[b * CPAD], BUFCAP);
    const unsigned* __restrict__ sb = buf + (size_t)b * BUFCAP;

    if (t < 256) hist[t] = 0;
    __syncthreads();

    for (int i = t; i < m; i += 1024) atomicAdd(&hist[sb[i] & 255], 1);
    __syncthreads();

    for (int o = 1; o < 256; o <<= 1) {
        int a = 0;
        if (t < 256 && t >= o) a = hist[t - o];
        __syncthreads();
        if (t < 256) hist[t] += a;
        __syncthreads();
    }
    if (t < 256) { lstart[t + 1] = hist[t]; lcur[t] = 0; }
    if (t == 0) lstart[0] = 0;
    __syncthreads();

    for (int i = t; i < m; i += 1024) {
        const unsigned v = sb[i];
        const int dl = v & 255;
        const int p  = atomicAdd(&lcur[dl], 1);
        const int pp = lstart[dl] + p;
        if (pp < LCAP) lcsr[pp] = (int)(v >> 8);
    }
    __syncthreads();

    const int gb   = boff[b];
    const int mtot = lstart[256];
    for (int i = t; i < mtot; i += 1024) csr[gb + i] = lcsr[i];
    if (t < nd) row_start[(b << 8) + t + 1] = gb + lstart[t + 1];
    if (b == 0 && t == 0) row_start[0] = 0;
}

// ---------------- Layer-1 aggregate: wave per dst, no-max softmax, VGPR-unlocked MLP ----------
// __launch_bounds__(256, 4): 4 blocks/CU min (16 waves/CU, 50% occ) -> <=128 VGPR budget.
// Removes the allocator's pressure-reason to sink the 4 unconditional uint4 gathers (R8/R12
// showed VGPR capped at 32 -> ~2 loads in flight). Trade 25pt occupancy for 3-4x per-wave MLP.
// Lane l: group g = l>>3 covers features 8*(l&7)..+7 (one uint4 = 8 bf16). Slots 0..31
// UNCONDITIONAL: pad slots carry sj=n (L1-hot row), pj=0. No-max softmax (shift-invariant;
// alphas O(1..10) by init scaling, exp safe in fp32).
__global__ __launch_bounds__(256, 4) void k_agg1(
    const int* __restrict__ row_start, const int* __restrict__ csr,
    const float* __restrict__ as1, const float* __restrict__ ad1,
    const unsigned* __restrict__ h1b,
    const float* __restrict__ b1, const float* __restrict__ W2,
    const float* __restrict__ a_s2, const float* __restrict__ a_d2,
    float* __restrict__ h2, float* __restrict__ as2, float* __restrict__ ad2)
{
    const int n = blockIdx.x * 4 + (threadIdx.x >> 6);
    const int j = threadIdx.x & 63;
    if (n >= N_NODES) return;

    const int g  = j >> 3;        // edge-phase group 0..7
    const int oq = (j & 7) << 2;  // u32 offset in row (4 u32 = 8 features)

    const int r0  = row_start[n];
    const int deg = row_start[n + 1] - r0;   // real in-edges; +1 implicit self
    const float ad = ad1[n];

    float acc0[8], acc1[8];
#pragma unroll
    for (int i = 0; i < 8; ++i) { acc0[i] = 0.f; acc1[i] = 0.f; }
    float den_l = 0.f;

#define FMA8(ACC, P, U)                                            \
    ACC[0] = fmaf(P, blo(U.x), ACC[0]); ACC[1] = fmaf(P, bhi(U.x), ACC[1]); \
    ACC[2] = fmaf(P, blo(U.y), ACC[2]); ACC[3] = fmaf(P, bhi(U.y), ACC[3]); \
    ACC[4] = fmaf(P, blo(U.z), ACC[4]); ACC[5] = fmaf(P, bhi(U.z), ACC[5]); \
    ACC[6] = fmaf(P, blo(U.w), ACC[6]); ACC[7] = fmaf(P, bhi(U.w), ACC[7]);
#define LD8(S) (*(const uint4*)(h1b + ((size_t)(S) << 5) + oq))

    if (deg <= 63) {               // fast path: edges + self in one wave chunk
        int sj = n;                // lanes >= deg: self row (lane 'deg' IS the self edge)
        if (j < deg) sj = csr[r0 + j];
        const float aj = as1[sj];                 // gather, issued first (valid for pads too)
        // slot shuffles + gather issues, independent of alphas
        const int s0 = __shfl(sj, g,      64);
        const int s1 = __shfl(sj, 8 + g,  64);
        const int s2 = __shfl(sj, 16 + g, 64);
        const int s3 = __shfl(sj, 24 + g, 64);
        const uint4 u0 = LD8(s0);
        const uint4 u1 = LD8(s1);
        const uint4 u2 = LD8(s2);
        const uint4 u3 = LD8(s3);
        // p while gathers are in flight (waits only on aj)
        float pj = 0.f;
        if (j <= deg) pj = __expf(lrelu(aj + ad));
        den_l = pj;
        const float p0 = __shfl(pj, g,      64);
        const float p1 = __shfl(pj, 8 + g,  64);
        const float p2 = __shfl(pj, 16 + g, 64);
        const float p3 = __shfl(pj, 24 + g, 64);
        FMA8(acc0, p0, u0) FMA8(acc1, p1, u1)
        FMA8(acc0, p2, u2) FMA8(acc1, p3, u3)

        const int tot = deg + 1;
        if (tot > 32) {            // rare (~3e-4 of nodes), wave-uniform guard
            const int s4 = __shfl(sj, 32 + g, 64);
            const int s5 = __shfl(sj, 40 + g, 64);
            const int s6 = __shfl(sj, 48 + g, 64);
            const int s7 = __shfl(sj, 56 + g, 64);
            const uint4 u4 = LD8(s4);
            const uint4 u5 = LD8(s5);
            const uint4 u6 = LD8(s6);
            const uint4 u7 = LD8(s7);
            const float p4 = __shfl(pj, 32 + g, 64);
            const float p5 = __shfl(pj, 40 + g, 64);
            const float p6 = __shfl(pj, 48 + g, 64);
            const float p7 = __shfl(pj, 56 + g, 64);
            FMA8(acc0, p4, u4) FMA8(acc1, p5, u5)
            FMA8(acc0, p6, u6) FMA8(acc1, p7, u7)
        }
    } else {                       // generic chunked path + explicit self (stat. never taken)
        {   // self edge: group 0 lanes cover all 8 feature-octs
            const float ps = __expf(lrelu(as1[n] + ad));
            if (j == 0) den_l += ps;
            if (g == 0) {
                const uint4 uv = LD8(n);
                FMA8(acc0, ps, uv)
            }
        }
        for (int cb = r0; cb < r0 + deg; cb += 64) {
            const int cnt = min(64, r0 + deg - cb);   // wave-uniform
            int sj = 0; float pj = 0.f;               // pad lanes: valid row 0, p = 0
            if (j < cnt) { sj = csr[cb + j]; pj = __expf(lrelu(as1[sj] + ad)); }
            den_l += pj;
            for (int base = 0; base < cnt; base += 16) {
                const int   sA = __shfl(sj, base + g, 64);
                const float pA = __shfl(pj, base + g, 64);
                const uint4 ua = LD8(sA);
                FMA8(acc0, pA, ua)
                if (base + 8 < cnt) {
                    const int   sB = __shfl(sj, base + 8 + g, 64);
                    const float pB = __shfl(pj, base + 8 + g, 64);
                    const uint4 ub = LD8(sB);
                    FMA8(acc1, pB, ub)
                }
            }
        }
    }
#undef FMA8
#undef LD8

    float den = den_l;
#pragma unroll
    for (int o = 32; o; o >>= 1) den += __shfl_xor(den, o, 64);

    // merge unroll chains, then sum the 8 edge-groups (lanes with equal j&7)
#pragma unroll
    for (int i = 0; i < 8; ++i) acc0[i] += acc1[i];
#pragma unroll
    for (int o = 8; o <= 32; o <<= 1) {
#pragma unroll
        for (int i = 0; i < 8; ++i) acc0[i] += __shfl_xor(acc0[i], o, 64);
    }

    // layer-1 epilogue + 64x2 layer-2 GEMM + alpha2 (features ob..ob+7 per lane)
    const float inv = 1.f / (den + 1e-16f);
    const int ob = (j & 7) << 3;
    const float4 b0 = *(const float4*)(b1 + ob);
    const float4 b4 = *(const float4*)(b1 + ob + 4);
    float v[8];
    v[0] = acc0[0] * inv + b0.x; v[1] = acc0[1] * inv + b0.y;
    v[2] = acc0[2] * inv + b0.z; v[3] = acc0[3] * inv + b0.w;
    v[4] = acc0[4] * inv + b4.x; v[5] = acc0[5] * inv + b4.y;
    v[6] = acc0[6] * inv + b4.z; v[7] = acc0[7] * inv + b4.w;
#pragma unroll
    for (int i = 0; i < 8; ++i) v[i] = v[i] > 0.f ? v[i] : 0.f;

    const float4* __restrict__ wq = (const float4*)(W2 + 2 * ob);  // rows ob..ob+7, 2 cols
    const float4 w0 = wq[0], w1 = wq[1], w2 = wq[2], w3 = wq[3];
    float c0 = v[0] * w0.x + v[1] * w0.z + v[2] * w1.x + v[3] * w1.z
             + v[4] * w2.x + v[5] * w2.z + v[6] * w3.x + v[7] * w3.z;
    float c1 = v[0] * w0.y + v[1] * w0.w + v[2] * w1.y + v[3] * w1.w
             + v[4] * w2.y + v[5] * w2.w + v[6] * w3.y + v[7] * w3.w;
#pragma unroll
    for (int o = 1; o <= 4; o <<= 1) {   // sum the 8 feature-octs within the group
        c0 += __shfl_xor(c0, o, 64);
        c1 += __shfl_xor(c1, o, 64);
    }
    if (j == 0) {
        h2[n * 2 + 0] = c0;
        h2[n * 2 + 1] = c1;
        as2[n] = c0 * a_s2[0] + c1 * a_s2[1];
        ad2[n] = c0 * a_d2[0] + c1 * a_d2[1];
    }
}

// ---------------- Layer-2 aggregate: wave per dst, no-max softmax, parallel dual gathers --------
__global__ __launch_bounds__(256) void k_agg2_wave(
    const int* __restrict__ row_start, const int* __restrict__ csr,
    const float* __restrict__ as2, const float* __restrict__ ad2,
    const float* __restrict__ h2, const float* __restrict__ b2,
    float* __restrict__ out)
{
    const int n = blockIdx.x * 4 + (threadIdx.x >> 6);
    const int j = threadIdx.x & 63;
    if (n >= N_NODES) return;
    const int r0  = row_start[n];
    const int deg = row_start[n + 1] - r0;
    const float ad = ad2[n];
    const float2* __restrict__ h22 = (const float2*)h2;

    float den_l = 0.f, x0 = 0.f, x1 = 0.f;
    if (deg <= 63) {
        int sj = n;                                 // lanes >= deg: self row
        if (j < deg) sj = csr[r0 + j];
        const float  aj = as2[sj];                  // both gathers in flight together
        const float2 hv = h22[sj];
        float p = 0.f;
        if (j <= deg) p = __expf(lrelu(aj + ad));
        den_l = p; x0 = p * hv.x; x1 = p * hv.y;
    } else {
        if (j == 0) {   // self edge
            const float p = __expf(lrelu(as2[n] + ad));
            const float2 hv = h22[n];
            den_l = p; x0 = p * hv.x; x1 = p * hv.y;
        }
        for (int idx = r0 + j; idx < r0 + deg; idx += 64) {
            const int s = csr[idx];
            const float p = __expf(lrelu(as2[s] + ad));
            const float2 hv = h22[s];
            den_l += p; x0 = fmaf(p, hv.x, x0); x1 = fmaf(p, hv.y, x1);
        }
    }
#pragma unroll
    for (int o = 32; o; o >>= 1) {
        den_l += __shfl_xor(den_l, o, 64);
        x0    += __shfl_xor(x0, o, 64);
        x1    += __shfl_xor(x1, o, 64);
    }
    if (j == 0) {
        const float inv = 1.f / (den_l + 1e-16f);
        out[n * 2 + 0] = x0 * inv + b2[0];
        out[n * 2 + 1] = x1 * inv + b2[1];
    }
}

extern "C" void kernel_launch(void* const* d_in, const int* in_sizes, int n_in,
                              void* d_out, int out_size, void* d_ws, size_t ws_size,
                              hipStream_t stream)
{
    const float* x    = (const float*)d_in[0];
    const int*   ei   = (const int*)d_in[1];
    const float* W1   = (const float*)d_in[2];
    const float* as1w = (const float*)d_in[3];
    const float* ad1w = (const float*)d_in[4];
    const float* b1   = (const float*)d_in[5];
    const float* W2   = (const float*)d_in[6];
    const float* as2w = (const float*)d_in[7];
    const float* ad2w = (const float*)d_in[8];
    const float* b2   = (const float*)d_in[9];
    float* out = (float*)d_out;

    float* ws = (float*)d_ws;
    size_t off = 0;
    unsigned* h1b = (unsigned*)(ws + off); off += (size_t)N_NODES * 32;  // 12.8 MB, node-major
    float* as1 = ws + off; off += N_NODES;
    float* ad1 = ws + off; off += N_NODES;
    float* h2  = ws + off; off += (size_t)N_NODES * 2;
    float* as2 = ws + off; off += N_NODES;
    float* ad2 = ws + off; off += N_NODES;
    int* gcur      = (int*)(ws + off); off += NBUCK * CPAD;              // 25 KB, zeroed
    unsigned* buf  = (unsigned*)(ws + off); off += (size_t)NBUCK * BUFCAP;  // 9.6 MB
    int* boff      = (int*)(ws + off); off += NBUCK + 1;
    int* row_start = (int*)(ws + off); off += N_NODES + 1;
    int* csr       = (int*)(ws + off); off += N_EDGES;

    hipMemsetAsync(gcur, 0, NBUCK * CPAD * sizeof(int), stream);

    k_gemm1           <<<(N_NODES + 63) / 64, 256, 0, stream>>>(x, W1, as1w, ad1w, h1b, as1, ad1);
    k_bucketize_staged<<<SB, 256, 0, stream>>>(ei, gcur, buf);
    k_bscan           <<<1, 512, 0, stream>>>(gcur, boff);
    k_csr_build       <<<NBUCK, 1024, 0, stream>>>(gcur, buf, boff, row_start, csr);
    k_agg1            <<<(N_NODES + 3) / 4, 256, 0, stream>>>(
        row_start, csr, as1, ad1, h1b, b1, W2, as2w, ad2w, h2, as2, ad2);
    k_agg2_wave       <<<(N_NODES + 3) / 4, 256, 0, stream>>>(row_start, csr, as2, ad2, h2, b2, out);
}

// Round 15
// 243.660 us; speedup vs baseline: 1.2946x; 1.0073x over previous
//
#include <hip/hip_runtime.h>
#include <math.h>

constexpr int N_NODES = 100000;
constexpr int N_EDGES = 1600000;
constexpr int F_IN    = 128;
constexpr int F_H     = 64;
constexpr float NEG_SLOPE = 0.2f;

constexpr int NBUCK  = (N_NODES + 255) / 256;  // 391 buckets of 256 dst nodes
constexpr int BUFCAP = 6144;                   // per-bucket stream cap (mean 4092, +32 sigma)
constexpr int LCAP   = 6144;
constexpr int CPAD   = 16;                     // gcur stride in ints: one 64B line per counter

// staged multisplit params
constexpr int SB   = 256;                      // staging blocks (75KB LDS -> 2 blocks/CU, all CUs)
constexpr int EPT  = 4;                        // edges per thread per round
constexpr int EPR  = 256 * EPT;                // 1024 edges per round
constexpr int G    = 16;                       // flush granularity = one 64B line
constexpr int BCAP = 48;                       // LDS bin capacity (15 carry + Poisson(2.62) tail)

__device__ inline float lrelu(float v) { return v > 0.f ? v : NEG_SLOPE * v; }
// bf16-pair unpack: u32 holds [lo = feature 2i, hi = feature 2i+1]
__device__ inline float blo(unsigned u) { return __uint_as_float(u << 16); }
__device__ inline float bhi(unsigned u) { return __uint_as_float(u & 0xFFFF0000u); }
// RNE float->bf16 (as high 16 bits)
__device__ inline unsigned bf16hi(float f) {
    unsigned u = __float_as_uint(f);
    return (u + 0x7FFFu + ((u >> 16) & 1u)) & 0xFFFF0000u;
}
__device__ inline unsigned bf16lo(float f) {
    unsigned u = __float_as_uint(f);
    return (u + 0x7FFFu + ((u >> 16) & 1u)) >> 16;
}

// ---------------- GEMM: block = 64 rows, 4 waves split the 64 features (16 each) ----------------
// h1b NODE-MAJOR (R8 layout): row = 32 u32 = 128B of bf16 pairs.
__global__ __launch_bounds__(256) void k_gemm1(
    const float* __restrict__ x, const float* __restrict__ W1,
    const float* __restrict__ a_s, const float* __restrict__ a_d,
    unsigned* __restrict__ h1b, float* __restrict__ as1, float* __restrict__ ad1)
{
    __shared__ float vsP[4][64];
    __shared__ float vdP[4][64];

    const int lane = threadIdx.x & 63;
    const int w    = __builtin_amdgcn_readfirstlane(threadIdx.x >> 6);  // SGPR wave id
    const int fo   = w * 16;                 // feature offset (wave-uniform)
    const int row  = blockIdx.x * 64 + lane;
    const bool valid = row < N_NODES;

    float acc[16];
#pragma unroll
    for (int i = 0; i < 16; ++i) acc[i] = 0.f;

    if (valid) {
        const float4* __restrict__ xr = (const float4*)(x + (size_t)row * F_IN);
        float4 xv = xr[0];
        for (int k4 = 0; k4 < F_IN / 4; ++k4) {
            const float4 xn = xr[(k4 + 1) & (F_IN / 4 - 1)];   // prefetch (wraps harmlessly)
            const float* __restrict__ wk = W1 + (size_t)k4 * 4 * F_H + fo;  // wave-uniform
#pragma unroll
            for (int kk = 0; kk < 4; ++kk) {
                const float xs = (kk == 0) ? xv.x : (kk == 1) ? xv.y : (kk == 2) ? xv.z : xv.w;
                const float* __restrict__ ws = wk + kk * F_H;   // scalar loads (SGPR base)
#pragma unroll
                for (int i = 0; i < 16; ++i)
                    acc[i] = fmaf(xs, ws[i], acc[i]);
            }
            xv = xn;
        }
    }

    // partial alphas over this wave's 16 features (fp32, pre-rounding)
    float vs = 0.f, vd = 0.f;
#pragma unroll
    for (int i = 0; i < 16; ++i) {
        vs = fmaf(acc[i], a_s[fo + i], vs);
        vd = fmaf(acc[i], a_d[fo + i], vd);
    }
    vsP[w][lane] = vs;
    vdP[w][lane] = vd;
    __syncthreads();
    if (w == 0 && valid) {
        as1[row] = vsP[0][lane] + vsP[1][lane] + vsP[2][lane] + vsP[3][lane];
        ad1[row] = vdP[0][lane] + vdP[1][lane] + vdP[2][lane] + vdP[3][lane];
    }

    if (valid) {
        // pack this wave's 16 features -> 8 u32 (bf16 RNE), write slice [8w, 8w+8)
        unsigned up[8];
#pragma unroll
        for (int i = 0; i < 8; ++i)
            up[i] = bf16lo(acc[2 * i]) | bf16hi(acc[2 * i + 1]);
        uint4* __restrict__ hr = (uint4*)(h1b + (size_t)row * 32 + w * 8);
        hr[0] = make_uint4(up[0], up[1], up[2], up[3]);
        hr[1] = make_uint4(up[4], up[5], up[6], up[7]);
    }
}

// ---------------- Staged multisplit bucketize: LDS bins, aligned 16-dword flushes ----------------
__global__ __launch_bounds__(256) void k_bucketize_staged(
    const int* __restrict__ ei, int* __restrict__ gcur, unsigned* __restrict__ buf)
{
    __shared__ unsigned bin_buf[NBUCK][BCAP];   // ~75 KB
    __shared__ int bin_cnt[NBUCK];

    const int t = threadIdx.x;
    for (int i = t; i < NBUCK; i += 256) bin_cnt[i] = 0;
    __syncthreads();

    const int per = N_EDGES / SB;               // 6250 exactly
    const int e0 = blockIdx.x * per;
    const int e1 = (blockIdx.x == SB - 1) ? N_EDGES : (e0 + per);

    int cs[EPT], cd[EPT];
#pragma unroll
    for (int q = 0; q < EPT; ++q) {
        const int i = e0 + q * 256 + t;
        cs[q] = (i < e1) ? ei[i] : -1;
        cd[q] = (i < e1) ? ei[N_EDGES + i] : 0;
    }

    for (int base = e0; base < e1; base += EPR) {
        int ls[EPT], ld[EPT];
#pragma unroll
        for (int q = 0; q < EPT; ++q) { ls[q] = cs[q]; ld[q] = cd[q]; }
        const int nbase = base + EPR;
        if (nbase < e1) {
#pragma unroll
            for (int q = 0; q < EPT; ++q) {
                const int i = nbase + q * 256 + t;
                cs[q] = (i < e1) ? ei[i] : -1;
                cd[q] = (i < e1) ? ei[N_EDGES + i] : 0;
            }
        }
        // insert into LDS bins
#pragma unroll
        for (int q = 0; q < EPT; ++q) {
            if (ls[q] >= 0) {
                const int b = ld[q] >> 8;
                const int pos = atomicAdd(&bin_cnt[b], 1);
                if (pos < BCAP)
                    bin_buf[b][pos] = ((unsigned)ls[q] << 8) | (unsigned)(ld[q] & 255);
            }
        }
        __syncthreads();
        // flush full 16-groups (aligned claims -> full-line writes)
        for (int bb = t; bb < NBUCK; bb += 256) {
            const int cnt = bin_cnt[bb];
            if (cnt >= G) {
                const int take = cnt & ~(G - 1);
                const int gbase = atomicAdd(&gcur[bb * CPAD], take);
                if (gbase + take <= BUFCAP) {
                    unsigned* __restrict__ dst = buf + (size_t)bb * BUFCAP + gbase;
                    const int src0 = cnt - take;
                    for (int u = 0; u < take; u += 4) {
                        uint4 v;
                        v.x = bin_buf[bb][src0 + u];
                        v.y = bin_buf[bb][src0 + u + 1];
                        v.z = bin_buf[bb][src0 + u + 2];
                        v.w = bin_buf[bb][src0 + u + 3];
                        *(uint4*)(dst + u) = v;
                    }
                }
                bin_cnt[bb] = cnt - take;
            }
        }
        __syncthreads();
    }
    // drain partial bins
    for (int bb = t; bb < NBUCK; bb += 256) {
        const int cnt = bin_cnt[bb];
        if (cnt > 0) {
            const int gbase = atomicAdd(&gcur[bb * CPAD], cnt);
            if (gbase + cnt <= BUFCAP) {
                unsigned* __restrict__ dst = buf + (size_t)bb * BUFCAP + gbase;
                for (int u = 0; u < cnt; ++u) dst[u] = bin_buf[bb][u];
            }
        }
    }
}

// ---------------- Bucket-total scan (391 values, one block) ----------------
__global__ __launch_bounds__(512) void k_bscan(const int* __restrict__ gcur, int* __restrict__ boff)
{
    __shared__ int sm[512];
    const int t = threadIdx.x;
    const int m = (t < NBUCK) ? min(gcur[t * CPAD], BUFCAP) : 0;
    sm[t] = m;
    __syncthreads();
    for (int o = 1; o < 512; o <<= 1) {
        int a = (t >= o) ? sm[t - o] : 0;
        __syncthreads();
        sm[t] += a;
        __syncthreads();
    }
    if (t < NBUCK) boff[t] = sm[t] - m;   // exclusive
}

// ---------------- Per-bucket CSR build in LDS, dense global write ----------------
__global__ __launch_bounds__(1024) void k_csr_build(
    const int* __restrict__ gcur, const unsigned* __restrict__ buf, const int* __restrict__ boff,
    int* __restrict__ row_start, int* __restrict__ csr)
{
    __shared__ int lcsr[LCAP];      // 24 KB
    __shared__ int hist[256];
    __shared__ int lstart[257];
    __shared__ int lcur[256];

    const int b  = blockIdx.x;
    const int t  = threadIdx.x;
    const int nd = min(256, N_NODES - (b << 8));
    const int m  = min(gcur[b * CPAD], BUFCAP);
    const unsigned* __restrict__ sb = buf + (size_t)b * BUFCAP;

    if (t < 256) hist[t] = 0;
    __syncthreads();

    for (int i = t; i < m; i += 1024) atomicAdd(&hist[sb[i] & 255], 1);
    __syncthreads();

    for (int o = 1; o < 256; o <<= 1) {
        int a = 0;
        if (t < 256 && t >= o) a = hist[t - o];
        __syncthreads();
        if (t < 256) hist[t] += a;
        __syncthreads();
    }
    if (t < 256) { lstart[t + 1] = hist[t]; lcur[t] = 0; }
    if (t == 0) lstart[0] = 0;
    __syncthreads();

    for (int i = t; i < m; i += 1024) {
        const unsigned v = sb[i];
        const int dl = v & 255;
        const int p  = atomicAdd(&lcur[dl], 1);
        const int pp = lstart[dl] + p;
        if (pp < LCAP) lcsr[pp] = (int)(v >> 8);
    }
    __syncthreads();

    const int gb   = boff[b];
    const int mtot = lstart[256];
    for (int i = t; i < mtot; i += 1024) csr[gb + i] = lcsr[i];
    if (t < nd) row_start[(b << 8) + t + 1] = gb + lstart[t + 1];
    if (b == 0 && t == 0) row_start[0] = 0;
}

// ---------------- Layer-1 aggregate: wave per dst, degree-guarded slot blocks ----------------
// Poisson(16) degrees: mean tot = 17, so unconditional 32-slot processing (R8) wasted ~47% of
// slot work on pads. Guards at 16/24/32 (wave-uniform; P(tot>16)=0.53, P(tot>24)=0.034,
// P(tot>32)=2e-4) cut average slot-blocks 4 -> 2.57. Guarded loads issue BEFORE the
// unconditional FMAs to keep gathers in flight. Pad lanes carry sj=n, pj=0 -> guard
// boundaries are semantically exact; den is computed from per-lane pj before any guard.
// No-max softmax (shift-invariant; alphas O(1..10) by init scaling, exp safe in fp32).
__global__ __launch_bounds__(256, 4) void k_agg1(
    const int* __restrict__ row_start, const int* __restrict__ csr,
    const float* __restrict__ as1, const float* __restrict__ ad1,
    const unsigned* __restrict__ h1b,
    const float* __restrict__ b1, const float* __restrict__ W2,
    const float* __restrict__ a_s2, const float* __restrict__ a_d2,
    float* __restrict__ h2, float* __restrict__ as2, float* __restrict__ ad2)
{
    const int n = blockIdx.x * 4 + (threadIdx.x >> 6);
    const int j = threadIdx.x & 63;
    if (n >= N_NODES) return;

    const int g  = j >> 3;        // edge-phase group 0..7
    const int oq = (j & 7) << 2;  // u32 offset in row (4 u32 = 8 features)

    const int r0  = row_start[n];
    const int deg = row_start[n + 1] - r0;   // real in-edges; +1 implicit self
    const float ad = ad1[n];

    float acc0[8], acc1[8];
#pragma unroll
    for (int i = 0; i < 8; ++i) { acc0[i] = 0.f; acc1[i] = 0.f; }
    float den_l = 0.f;

#define FMA8(ACC, P, U)                                            \
    ACC[0] = fmaf(P, blo(U.x), ACC[0]); ACC[1] = fmaf(P, bhi(U.x), ACC[1]); \
    ACC[2] = fmaf(P, blo(U.y), ACC[2]); ACC[3] = fmaf(P, bhi(U.y), ACC[3]); \
    ACC[4] = fmaf(P, blo(U.z), ACC[4]); ACC[5] = fmaf(P, bhi(U.z), ACC[5]); \
    ACC[6] = fmaf(P, blo(U.w), ACC[6]); ACC[7] = fmaf(P, bhi(U.w), ACC[7]);
#define LD8(S) (*(const uint4*)(h1b + ((size_t)(S) << 5) + oq))

    if (deg <= 63) {               // fast path: edges + self in one wave chunk
        int sj = n;                // lanes >= deg: self row (lane 'deg' IS the self edge)
        if (j < deg) sj = csr[r0 + j];
        const float aj = as1[sj];                 // gather, issued first (valid for pads too)
        // slots 0-15: unconditional (covers tot <= 16, 47% of nodes entirely)
        const int s0 = __shfl(sj, g,      64);
        const int s1 = __shfl(sj, 8 + g,  64);
        const uint4 u0 = LD8(s0);
        const uint4 u1 = LD8(s1);
        // p while gathers are in flight (waits only on aj)
        float pj = 0.f;
        if (j <= deg) pj = __expf(lrelu(aj + ad));
        den_l = pj;
        const float p0 = __shfl(pj, g,      64);
        const float p1 = __shfl(pj, 8 + g,  64);

        const int tot = deg + 1;
        const bool t16 = tot > 16, t24 = tot > 24, t32 = tot > 32;
        // guarded loads issued early, FMAs later (keep loads in flight across p0/p1 FMAs)
        int s2, s3; uint4 u2, u3; float p2, p3;
        if (t16) { s2 = __shfl(sj, 16 + g, 64); u2 = LD8(s2); p2 = __shfl(pj, 16 + g, 64); }
        if (t24) { s3 = __shfl(sj, 24 + g, 64); u3 = LD8(s3); p3 = __shfl(pj, 24 + g, 64); }
        FMA8(acc0, p0, u0) FMA8(acc1, p1, u1)
        if (t16) { FMA8(acc0, p2, u2) }
        if (t24) { FMA8(acc1, p3, u3) }
        if (t32) {                 // rare (~2e-4 of nodes): loop the remaining slots
            for (int base = 32; base < tot; base += 8) {
                const int   sA = __shfl(sj, base + g, 64);   // src lane <= 63
                const float pA = __shfl(pj, base + g, 64);
                const uint4 ua = LD8(sA);
                FMA8(acc0, pA, ua)
            }
        }
    } else {                       // generic chunked path + explicit self (stat. never taken)
        {   // self edge: group 0 lanes cover all 8 feature-octs
            const float ps = __expf(lrelu(as1[n] + ad));
            if (j == 0) den_l += ps;
            if (g == 0) {
                const uint4 uv = LD8(n);
                FMA8(acc0, ps, uv)
            }
        }
        for (int cb = r0; cb < r0 + deg; cb += 64) {
            const int cnt = min(64, r0 + deg - cb);   // wave-uniform
            int sj = 0; float pj = 0.f;               // pad lanes: valid row 0, p = 0
            if (j < cnt) { sj = csr[cb + j]; pj = __expf(lrelu(as1[sj] + ad)); }
            den_l += pj;
            for (int base = 0; base < cnt; base += 16) {
                const int   sA = __shfl(sj, base + g, 64);
                const float pA = __shfl(pj, base + g, 64);
                const uint4 ua = LD8(sA);
                FMA8(acc0, pA, ua)
                if (base + 8 < cnt) {
                    const int   sB = __shfl(sj, base + 8 + g, 64);
                    const float pB = __shfl(pj, base + 8 + g, 64);
                    const uint4 ub = LD8(sB);
                    FMA8(acc1, pB, ub)
                }
            }
        }
    }
#undef FMA8
#undef LD8

    float den = den_l;
#pragma unroll
    for (int o = 32; o; o >>= 1) den += __shfl_xor(den, o, 64);

    // merge unroll chains, then sum the 8 edge-groups (lanes with equal j&7)
#pragma unroll
    for (int i = 0; i < 8; ++i) acc0[i] += acc1[i];
#pragma unroll
    for (int o = 8; o <= 32; o <<= 1) {
#pragma unroll
        for (int i = 0; i < 8; ++i) acc0[i] += __shfl_xor(acc0[i], o, 64);
    }

    // layer-1 epilogue + 64x2 layer-2 GEMM + alpha2 (features ob..ob+7 per lane)
    const float inv = 1.f / (den + 1e-16f);
    const int ob = (j & 7) << 3;
    const float4 b0 = *(const float4*)(b1 + ob);
    const float4 b4 = *(const float4*)(b1 + ob + 4);
    float v[8];
    v[0] = acc0[0] * inv + b0.x; v[1] = acc0[1] * inv + b0.y;
    v[2] = acc0[2] * inv + b0.z; v[3] = acc0[3] * inv + b0.w;
    v[4] = acc0[4] * inv + b4.x; v[5] = acc0[5] * inv + b4.y;
    v[6] = acc0[6] * inv + b4.z; v[7] = acc0[7] * inv + b4.w;
#pragma unroll
    for (int i = 0; i < 8; ++i) v[i] = v[i] > 0.f ? v[i] : 0.f;

    const float4* __restrict__ wq = (const float4*)(W2 + 2 * ob);  // rows ob..ob+7, 2 cols
    const float4 w0 = wq[0], w1 = wq[1], w2 = wq[2], w3 = wq[3];
    float c0 = v[0] * w0.x + v[1] * w0.z + v[2] * w1.x + v[3] * w1.z
             + v[4] * w2.x + v[5] * w2.z + v[6] * w3.x + v[7] * w3.z;
    float c1 = v[0] * w0.y + v[1] * w0.w + v[2] * w1.y + v[3] * w1.w
             + v[4] * w2.y + v[5] * w2.w + v[6] * w3.y + v[7] * w3.w;
#pragma unroll
    for (int o = 1; o <= 4; o <<= 1) {   // sum the 8 feature-octs within the group
        c0 += __shfl_xor(c0, o, 64);
        c1 += __shfl_xor(c1, o, 64);
    }
    if (j == 0) {
        h2[n * 2 + 0] = c0;
        h2[n * 2 + 1] = c1;
        as2[n] = c0 * a_s2[0] + c1 * a_s2[1];
        ad2[n] = c0 * a_d2[0] + c1 * a_d2[1];
    }
}

// ---------------- Layer-2 aggregate: wave per dst, no-max softmax, parallel dual gathers --------
__global__ __launch_bounds__(256) void k_agg2_wave(
    const int* __restrict__ row_start, const int* __restrict__ csr,
    const float* __restrict__ as2, const float* __restrict__ ad2,
    const float* __restrict__ h2, const float* __restrict__ b2,
    float* __restrict__ out)
{
    const int n = blockIdx.x * 4 + (threadIdx.x >> 6);
    const int j = threadIdx.x & 63;
    if (n >= N_NODES) return;
    const int r0  = row_start[n];
    const int deg = row_start[n + 1] - r0;
    const float ad = ad2[n];
    const float2* __restrict__ h22 = (const float2*)h2;

    float den_l = 0.f, x0 = 0.f, x1 = 0.f;
    if (deg <= 63) {
        int sj = n;                                 // lanes >= deg: self row
        if (j < deg) sj = csr[r0 + j];
        const float  aj = as2[sj];                  // both gathers in flight together
        const float2 hv = h22[sj];
        float p = 0.f;
        if (j <= deg) p = __expf(lrelu(aj + ad));
        den_l = p; x0 = p * hv.x; x1 = p * hv.y;
    } else {
        if (j == 0) {   // self edge
            const float p = __expf(lrelu(as2[n] + ad));
            const float2 hv = h22[n];
            den_l = p; x0 = p * hv.x; x1 = p * hv.y;
        }
        for (int idx = r0 + j; idx < r0 + deg; idx += 64) {
            const int s = csr[idx];
            const float p = __expf(lrelu(as2[s] + ad));
            const float2 hv = h22[s];
            den_l += p; x0 = fmaf(p, hv.x, x0); x1 = fmaf(p, hv.y, x1);
        }
    }
#pragma unroll
    for (int o = 32; o; o >>= 1) {
        den_l += __shfl_xor(den_l, o, 64);
        x0    += __shfl_xor(x0, o, 64);
        x1    += __shfl_xor(x1, o, 64);
    }
    if (j == 0) {
        const float inv = 1.f / (den_l + 1e-16f);
        out[n * 2 + 0] = x0 * inv + b2[0];
        out[n * 2 + 1] = x1 * inv + b2[1];
    }
}

extern "C" void kernel_launch(void* const* d_in, const int* in_sizes, int n_in,
                              void* d_out, int out_size, void* d_ws, size_t ws_size,
                              hipStream_t stream)
{
    const float* x    = (const float*)d_in[0];
    const int*   ei   = (const int*)d_in[1];
    const float* W1   = (const float*)d_in[2];
    const float* as1w = (const float*)d_in[3];
    const float* ad1w = (const float*)d_in[4];
    const float* b1   = (const float*)d_in[5];
    const float* W2   = (const float*)d_in[6];
    const float* as2w = (const float*)d_in[7];
    const float* ad2w = (const float*)d_in[8];
    const float* b2   = (const float*)d_in[9];
    float* out = (float*)d_out;

    float* ws = (float*)d_ws;
    size_t off = 0;
    unsigned* h1b = (unsigned*)(ws + off); off += (size_t)N_NODES * 32;  // 12.8 MB, node-major
    float* as1 = ws + off; off += N_NODES;
    float* ad1 = ws + off; off += N_NODES;
    float* h2  = ws + off; off += (size_t)N_NODES * 2;
    float* as2 = ws + off; off += N_NODES;
    float* ad2 = ws + off; off += N_NODES;
    int* gcur      = (int*)(ws + off); off += NBUCK * CPAD;              // 25 KB, zeroed
    unsigned* buf  = (unsigned*)(ws + off); off += (size_t)NBUCK * BUFCAP;  // 9.6 MB
    int* boff      = (int*)(ws + off); off += NBUCK + 1;
    int* row_start = (int*)(ws + off); off += N_NODES + 1;
    int* csr       = (int*)(ws + off); off += N_EDGES;

    hipMemsetAsync(gcur, 0, NBUCK * CPAD * sizeof(int), stream);

    k_gemm1           <<<(N_NODES + 63) / 64, 256, 0, stream>>>(x, W1, as1w, ad1w, h1b, as1, ad1);
    k_bucketize_staged<<<SB, 256, 0, stream>>>(ei, gcur, buf);
    k_bscan           <<<1, 512, 0, stream>>>(gcur, boff);
    k_csr_build       <<<NBUCK, 1024, 0, stream>>>(gcur, buf, boff, row_start, csr);
    k_agg1            <<<(N_NODES + 3) / 4, 256, 0, stream>>>(
        row_start, csr, as1, ad1, h1b, b1, W2, as2w, ad2w, h2, as2, ad2);
    k_agg2_wave       <<<(N_NODES + 3) / 4, 256, 0, stream>>>(row_start, csr, as2, ad2, h2, b2, out);
}

// Round 16
// 238.005 us; speedup vs baseline: 1.3253x; 1.0238x over previous
//
#include <hip/hip_runtime.h>
#include <math.h>

constexpr int N_NODES = 100000;
constexpr int N_EDGES = 1600000;
constexpr int F_IN    = 128;
constexpr int F_H     = 64;
constexpr float NEG_SLOPE = 0.2f;

constexpr int NBUCK  = (N_NODES + 255) / 256;  // 391 buckets of 256 dst nodes
constexpr int BUFCAP = 6144;                   // per-bucket stream cap (mean 4092, +32 sigma)
constexpr int LCAP   = 6144;
constexpr int CPAD   = 16;                     // gcur stride in ints: one 64B line per counter

// staged multisplit params
constexpr int SB   = 256;                      // bucketize-role blocks (dispatched FIRST)
constexpr int EPT  = 4;                        // edges per thread per round
constexpr int EPR  = 256 * EPT;                // 1024 edges per round
constexpr int G    = 16;                       // flush granularity = one 64B line
constexpr int BCAP = 48;                       // LDS bin capacity (15 carry + Poisson(2.62) tail)

constexpr int GEMM_BLOCKS = (N_NODES + 63) / 64;   // 1563 gemm-role blocks

__device__ inline float lrelu(float v) { return v > 0.f ? v : NEG_SLOPE * v; }
// bf16-pair unpack: u32 holds [lo = feature 2i, hi = feature 2i+1]
__device__ inline float blo(unsigned u) { return __uint_as_float(u << 16); }
__device__ inline float bhi(unsigned u) { return __uint_as_float(u & 0xFFFF0000u); }
// RNE float->bf16 (as high 16 bits)
__device__ inline unsigned bf16hi(float f) {
    unsigned u = __float_as_uint(f);
    return (u + 0x7FFFu + ((u >> 16) & 1u)) & 0xFFFF0000u;
}
__device__ inline unsigned bf16lo(float f) {
    unsigned u = __float_as_uint(f);
    return (u + 0x7FFFu + ((u >> 16) & 1u)) >> 16;
}

// ---------------- FUSED: bucketize (blocks 0..SB-1) + GEMM1 (blocks SB..) ----------------
// The two roles are data-independent (bucketize: edge_index; gemm1: x,W1) -> co-resident blocks
// overlap the ~30us bucketize with the ~45us gemm1 instead of serializing them.
// Bucketize blocks go FIRST so they dispatch immediately. LDS is a 75KB role-union; gemm-role
// blocks pack 2/CU (16 waves/CU) which gemm1 tolerates (its x-loads hide under co-resident waves).
__global__ __launch_bounds__(256) void k_gemm1_bucketize(
    const float* __restrict__ x, const float* __restrict__ W1,
    const float* __restrict__ a_s, const float* __restrict__ a_d,
    unsigned* __restrict__ h1b, float* __restrict__ as1, float* __restrict__ ad1,
    const int* __restrict__ ei, int* __restrict__ gcur, unsigned* __restrict__ buf)
{
    __shared__ union SM {
        struct { unsigned bin_buf[NBUCK][BCAP]; int bin_cnt[NBUCK]; } bk;  // ~75 KB
        struct { float vsP[4][64]; float vdP[4][64]; } gm;                  // 2 KB
    } sm;

    const int t = threadIdx.x;

    if (blockIdx.x < SB) {
        // ================= bucketize role =================
        for (int i = t; i < NBUCK; i += 256) sm.bk.bin_cnt[i] = 0;
        __syncthreads();

        const int per = N_EDGES / SB;               // 6250 exactly
        const int e0 = blockIdx.x * per;
        const int e1 = (blockIdx.x == SB - 1) ? N_EDGES : (e0 + per);

        int cs[EPT], cd[EPT];
#pragma unroll
        for (int q = 0; q < EPT; ++q) {
            const int i = e0 + q * 256 + t;
            cs[q] = (i < e1) ? ei[i] : -1;
            cd[q] = (i < e1) ? ei[N_EDGES + i] : 0;
        }

        for (int base = e0; base < e1; base += EPR) {
            int ls[EPT], ld[EPT];
#pragma unroll
            for (int q = 0; q < EPT; ++q) { ls[q] = cs[q]; ld[q] = cd[q]; }
            const int nbase = base + EPR;
            if (nbase < e1) {
#pragma unroll
                for (int q = 0; q < EPT; ++q) {
                    const int i = nbase + q * 256 + t;
                    cs[q] = (i < e1) ? ei[i] : -1;
                    cd[q] = (i < e1) ? ei[N_EDGES + i] : 0;
                }
            }
            // insert into LDS bins
#pragma unroll
            for (int q = 0; q < EPT; ++q) {
                if (ls[q] >= 0) {
                    const int b = ld[q] >> 8;
                    const int pos = atomicAdd(&sm.bk.bin_cnt[b], 1);
                    if (pos < BCAP)
                        sm.bk.bin_buf[b][pos] = ((unsigned)ls[q] << 8) | (unsigned)(ld[q] & 255);
                }
            }
            __syncthreads();
            // flush full 16-groups (aligned claims -> full-line writes)
            for (int bb = t; bb < NBUCK; bb += 256) {
                const int cnt = sm.bk.bin_cnt[bb];
                if (cnt >= G) {
                    const int take = cnt & ~(G - 1);
                    const int gbase = atomicAdd(&gcur[bb * CPAD], take);
                    if (gbase + take <= BUFCAP) {
                        unsigned* __restrict__ dst = buf + (size_t)bb * BUFCAP + gbase;
                        const int src0 = cnt - take;
                        for (int u = 0; u < take; u += 4) {
                            uint4 v;
                            v.x = sm.bk.bin_buf[bb][src0 + u];
                            v.y = sm.bk.bin_buf[bb][src0 + u + 1];
                            v.z = sm.bk.bin_buf[bb][src0 + u + 2];
                            v.w = sm.bk.bin_buf[bb][src0 + u + 3];
                            *(uint4*)(dst + u) = v;
                        }
                    }
                    sm.bk.bin_cnt[bb] = cnt - take;
                }
            }
            __syncthreads();
        }
        // drain partial bins
        for (int bb = t; bb < NBUCK; bb += 256) {
            const int cnt = sm.bk.bin_cnt[bb];
            if (cnt > 0) {
                const int gbase = atomicAdd(&gcur[bb * CPAD], cnt);
                if (gbase + cnt <= BUFCAP) {
                    unsigned* __restrict__ dst = buf + (size_t)bb * BUFCAP + gbase;
                    for (int u = 0; u < cnt; ++u) dst[u] = sm.bk.bin_buf[bb][u];
                }
            }
        }
        return;
    }

    // ================= gemm1 role =================
    const int lane = t & 63;
    const int w    = __builtin_amdgcn_readfirstlane(t >> 6);  // SGPR wave id
    const int fo   = w * 16;                                  // feature offset (wave-uniform)
    const int row  = (blockIdx.x - SB) * 64 + lane;
    const bool valid = row < N_NODES;

    float acc[16];
#pragma unroll
    for (int i = 0; i < 16; ++i) acc[i] = 0.f;

    if (valid) {
        const float4* __restrict__ xr = (const float4*)(x + (size_t)row * F_IN);
        float4 xv = xr[0];
        for (int k4 = 0; k4 < F_IN / 4; ++k4) {
            const float4 xn = xr[(k4 + 1) & (F_IN / 4 - 1)];   // prefetch (wraps harmlessly)
            const float* __restrict__ wk = W1 + (size_t)k4 * 4 * F_H + fo;  // wave-uniform
#pragma unroll
            for (int kk = 0; kk < 4; ++kk) {
                const float xs = (kk == 0) ? xv.x : (kk == 1) ? xv.y : (kk == 2) ? xv.z : xv.w;
                const float* __restrict__ ws = wk + kk * F_H;   // scalar loads (SGPR base)
#pragma unroll
                for (int i = 0; i < 16; ++i)
                    acc[i] = fmaf(xs, ws[i], acc[i]);
            }
            xv = xn;
        }
    }

    // partial alphas over this wave's 16 features (fp32, pre-rounding)
    float vs = 0.f, vd = 0.f;
#pragma unroll
    for (int i = 0; i < 16; ++i) {
        vs = fmaf(acc[i], a_s[fo + i], vs);
        vd = fmaf(acc[i], a_d[fo + i], vd);
    }
    sm.gm.vsP[w][lane] = vs;
    sm.gm.vdP[w][lane] = vd;
    __syncthreads();
    if (w == 0 && valid) {
        as1[row] = sm.gm.vsP[0][lane] + sm.gm.vsP[1][lane] + sm.gm.vsP[2][lane] + sm.gm.vsP[3][lane];
        ad1[row] = sm.gm.vdP[0][lane] + sm.gm.vdP[1][lane] + sm.gm.vdP[2][lane] + sm.gm.vdP[3][lane];
    }

    if (valid) {
        // pack this wave's 16 features -> 8 u32 (bf16 RNE), write slice [8w, 8w+8)
        unsigned up[8];
#pragma unroll
        for (int i = 0; i < 8; ++i)
            up[i] = bf16lo(acc[2 * i]) | bf16hi(acc[2 * i + 1]);
        uint4* __restrict__ hr = (uint4*)(h1b + (size_t)row * 32 + w * 8);
        hr[0] = make_uint4(up[0], up[1], up[2], up[3]);
        hr[1] = make_uint4(up[4], up[5], up[6], up[7]);
    }
}

// ---------------- Per-bucket CSR build in LDS + inlined bucket-prefix scan ----------------
// bscan kernel folded in: each block recomputes the exclusive prefix over buckets < b
// (<=391 L2-hot loads + 16-wave reduce) -- removes one kernel + launch.
__global__ __launch_bounds__(1024) void k_csr_build(
    const int* __restrict__ gcur, const unsigned* __restrict__ buf,
    int* __restrict__ row_start, int* __restrict__ csr)
{
    __shared__ int lcsr[LCAP];      // 24 KB
    __shared__ int hist[256];
    __shared__ int lstart[257];
    __shared__ int lcur[256];
    __shared__ int redsm[16];
    __shared__ int gb_sm;

    const int b  = blockIdx.x;
    const int t  = threadIdx.x;
    const int nd = min(256, N_NODES - (b << 8));
    const int m  = min(gcur[b * CPAD], BUFCAP);
    const unsigned* __restrict__ sb = buf + (size_t)b * BUFCAP;

    // exclusive prefix over buckets < b
    int part = 0;
    for (int i = t; i < b; i += 1024) part += min(gcur[i * CPAD], BUFCAP);
#pragma unroll
    for (int o = 32; o; o >>= 1) part += __shfl_xor(part, o, 64);
    if ((t & 63) == 0) redsm[t >> 6] = part;
    if (t < 256) hist[t] = 0;
    __syncthreads();
    if (t == 0) {
        int s = 0;
#pragma unroll
        for (int i = 0; i < 16; ++i) s += redsm[i];
        gb_sm = s;
    }
    __syncthreads();

    for (int i = t; i < m; i += 1024) atomicAdd(&hist[sb[i] & 255], 1);
    __syncthreads();

    for (int o = 1; o < 256; o <<= 1) {
        int a = 0;
        if (t < 256 && t >= o) a = hist[t - o];
        __syncthreads();
        if (t < 256) hist[t] += a;
        __syncthreads();
    }
    if (t < 256) { lstart[t + 1] = hist[t]; lcur[t] = 0; }
    if (t == 0) lstart[0] = 0;
    __syncthreads();

    for (int i = t; i < m; i += 1024) {
        const unsigned v = sb[i];
        const int dl = v & 255;
        const int p  = atomicAdd(&lcur[dl], 1);
        const int pp = lstart[dl] + p;
        if (pp < LCAP) lcsr[pp] = (int)(v >> 8);
    }
    __syncthreads();

    const int gb   = gb_sm;
    const int mtot = lstart[256];
    for (int i = t; i < mtot; i += 1024) csr[gb + i] = lcsr[i];
    if (t < nd) row_start[(b << 8) + t + 1] = gb + lstart[t + 1];
    if (b == 0 && t == 0) row_start[0] = 0;
}

// ---------------- Layer-1 aggregate: wave per dst, degree-guarded slot blocks ----------------
// (R15-verified: 56us, -8% vs unguarded.) Guards at 16/24/32 (wave-uniform); pad lanes carry
// sj=n, pj=0 -> boundaries exact. No-max softmax (shift-invariant; alphas O(1..10), fp32-safe).
__global__ __launch_bounds__(256, 4) void k_agg1(
    const int* __restrict__ row_start, const int* __restrict__ csr,
    const float* __restrict__ as1, const float* __restrict__ ad1,
    const unsigned* __restrict__ h1b,
    const float* __restrict__ b1, const float* __restrict__ W2,
    const float* __restrict__ a_s2, const float* __restrict__ a_d2,
    float* __restrict__ h2, float* __restrict__ as2, float* __restrict__ ad2)
{
    const int n = blockIdx.x * 4 + (threadIdx.x >> 6);
    const int j = threadIdx.x & 63;
    if (n >= N_NODES) return;

    const int g  = j >> 3;        // edge-phase group 0..7
    const int oq = (j & 7) << 2;  // u32 offset in row (4 u32 = 8 features)

    const int r0  = row_start[n];
    const int deg = row_start[n + 1] - r0;   // real in-edges; +1 implicit self
    const float ad = ad1[n];

    float acc0[8], acc1[8];
#pragma unroll
    for (int i = 0; i < 8; ++i) { acc0[i] = 0.f; acc1[i] = 0.f; }
    float den_l = 0.f;

#define FMA8(ACC, P, U)                                            \
    ACC[0] = fmaf(P, blo(U.x), ACC[0]); ACC[1] = fmaf(P, bhi(U.x), ACC[1]); \
    ACC[2] = fmaf(P, blo(U.y), ACC[2]); ACC[3] = fmaf(P, bhi(U.y), ACC[3]); \
    ACC[4] = fmaf(P, blo(U.z), ACC[4]); ACC[5] = fmaf(P, bhi(U.z), ACC[5]); \
    ACC[6] = fmaf(P, blo(U.w), ACC[6]); ACC[7] = fmaf(P, bhi(U.w), ACC[7]);
#define LD8(S) (*(const uint4*)(h1b + ((size_t)(S) << 5) + oq))

    if (deg <= 63) {               // fast path: edges + self in one wave chunk
        int sj = n;                // lanes >= deg: self row (lane 'deg' IS the self edge)
        if (j < deg) sj = csr[r0 + j];
        const float aj = as1[sj];                 // gather, issued first (valid for pads too)
        // slots 0-15: unconditional (covers tot <= 16, 47% of nodes entirely)
        const int s0 = __shfl(sj, g,      64);
        const int s1 = __shfl(sj, 8 + g,  64);
        const uint4 u0 = LD8(s0);
        const uint4 u1 = LD8(s1);
        // p while gathers are in flight (waits only on aj)
        float pj = 0.f;
        if (j <= deg) pj = __expf(lrelu(aj + ad));
        den_l = pj;
        const float p0 = __shfl(pj, g,      64);
        const float p1 = __shfl(pj, 8 + g,  64);

        const int tot = deg + 1;
        const bool t16 = tot > 16, t24 = tot > 24, t32 = tot > 32;
        // guarded loads issued early, FMAs later (keep loads in flight across p0/p1 FMAs)
        int s2, s3; uint4 u2, u3; float p2, p3;
        if (t16) { s2 = __shfl(sj, 16 + g, 64); u2 = LD8(s2); p2 = __shfl(pj, 16 + g, 64); }
        if (t24) { s3 = __shfl(sj, 24 + g, 64); u3 = LD8(s3); p3 = __shfl(pj, 24 + g, 64); }
        FMA8(acc0, p0, u0) FMA8(acc1, p1, u1)
        if (t16) { FMA8(acc0, p2, u2) }
        if (t24) { FMA8(acc1, p3, u3) }
        if (t32) {                 // rare (~2e-4 of nodes): loop the remaining slots
            for (int base = 32; base < tot; base += 8) {
                const int   sA = __shfl(sj, base + g, 64);   // src lane <= 63
                const float pA = __shfl(pj, base + g, 64);
                const uint4 ua = LD8(sA);
                FMA8(acc0, pA, ua)
            }
        }
    } else {                       // generic chunked path + explicit self (stat. never taken)
        {   // self edge: group 0 lanes cover all 8 feature-octs
            const float ps = __expf(lrelu(as1[n] + ad));
            if (j == 0) den_l += ps;
            if (g == 0) {
                const uint4 uv = LD8(n);
                FMA8(acc0, ps, uv)
            }
        }
        for (int cb = r0; cb < r0 + deg; cb += 64) {
            const int cnt = min(64, r0 + deg - cb);   // wave-uniform
            int sj = 0; float pj = 0.f;               // pad lanes: valid row 0, p = 0
            if (j < cnt) { sj = csr[cb + j]; pj = __expf(lrelu(as1[sj] + ad)); }
            den_l += pj;
            for (int base = 0; base < cnt; base += 16) {
                const int   sA = __shfl(sj, base + g, 64);
                const float pA = __shfl(pj, base + g, 64);
                const uint4 ua = LD8(sA);
                FMA8(acc0, pA, ua)
                if (base + 8 < cnt) {
                    const int   sB = __shfl(sj, base + 8 + g, 64);
                    const float pB = __shfl(pj, base + 8 + g, 64);
                    const uint4 ub = LD8(sB);
                    FMA8(acc1, pB, ub)
                }
            }
        }
    }
#undef FMA8
#undef LD8

    float den = den_l;
#pragma unroll
    for (int o = 32; o; o >>= 1) den += __shfl_xor(den, o, 64);

    // merge unroll chains, then sum the 8 edge-groups (lanes with equal j&7)
#pragma unroll
    for (int i = 0; i < 8; ++i) acc0[i] += acc1[i];
#pragma unroll
    for (int o = 8; o <= 32; o <<= 1) {
#pragma unroll
        for (int i = 0; i < 8; ++i) acc0[i] += __shfl_xor(acc0[i], o, 64);
    }

    // layer-1 epilogue + 64x2 layer-2 GEMM + alpha2 (features ob..ob+7 per lane)
    const float inv = 1.f / (den + 1e-16f);
    const int ob = (j & 7) << 3;
    const float4 b0 = *(const float4*)(b1 + ob);
    const float4 b4 = *(const float4*)(b1 + ob + 4);
    float v[8];
    v[0] = acc0[0] * inv + b0.x; v[1] = acc0[1] * inv + b0.y;
    v[2] = acc0[2] * inv + b0.z; v[3] = acc0[3] * inv + b0.w;
    v[4] = acc0[4] * inv + b4.x; v[5] = acc0[5] * inv + b4.y;
    v[6] = acc0[6] * inv + b4.z; v[7] = acc0[7] * inv + b4.w;
#pragma unroll
    for (int i = 0; i < 8; ++i) v[i] = v[i] > 0.f ? v[i] : 0.f;

    const float4* __restrict__ wq = (const float4*)(W2 + 2 * ob);  // rows ob..ob+7, 2 cols
    const float4 w0 = wq[0], w1 = wq[1], w2 = wq[2], w3 = wq[3];
    float c0 = v[0] * w0.x + v[1] * w0.z + v[2] * w1.x + v[3] * w1.z
             + v[4] * w2.x + v[5] * w2.z + v[6] * w3.x + v[7] * w3.z;
    float c1 = v[0] * w0.y + v[1] * w0.w + v[2] * w1.y + v[3] * w1.w
             + v[4] * w2.y + v[5] * w2.w + v[6] * w3.y + v[7] * w3.w;
#pragma unroll
    for (int o = 1; o <= 4; o <<= 1) {   // sum the 8 feature-octs within the group
        c0 += __shfl_xor(c0, o, 64);
        c1 += __shfl_xor(c1, o, 64);
    }
    if (j == 0) {
        h2[n * 2 + 0] = c0;
        h2[n * 2 + 1] = c1;
        as2[n] = c0 * a_s2[0] + c1 * a_s2[1];
        ad2[n] = c0 * a_d2[0] + c1 * a_d2[1];
    }
}

// ---------------- Layer-2 aggregate: wave per dst, no-max softmax, parallel dual gathers --------
__global__ __launch_bounds__(256) void k_agg2_wave(
    const int* __restrict__ row_start, const int* __restrict__ csr,
    const float* __restrict__ as2, const float* __restrict__ ad2,
    const float* __restrict__ h2, const float* __restrict__ b2,
    float* __restrict__ out)
{
    const int n = blockIdx.x * 4 + (threadIdx.x >> 6);
    const int j = threadIdx.x & 63;
    if (n >= N_NODES) return;
    const int r0  = row_start[n];
    const int deg = row_start[n + 1] - r0;
    const float ad = ad2[n];
    const float2* __restrict__ h22 = (const float2*)h2;

    float den_l = 0.f, x0 = 0.f, x1 = 0.f;
    if (deg <= 63) {
        int sj = n;                                 // lanes >= deg: self row
        if (j < deg) sj = csr[r0 + j];
        const float  aj = as2[sj];                  // both gathers in flight together
        const float2 hv = h22[sj];
        float p = 0.f;
        if (j <= deg) p = __expf(lrelu(aj + ad));
        den_l = p; x0 = p * hv.x; x1 = p * hv.y;
    } else {
        if (j == 0) {   // self edge
            const float p = __expf(lrelu(as2[n] + ad));
            const float2 hv = h22[n];
            den_l = p; x0 = p * hv.x; x1 = p * hv.y;
        }
        for (int idx = r0 + j; idx < r0 + deg; idx += 64) {
            const int s = csr[idx];
            const float p = __expf(lrelu(as2[s] + ad));
            const float2 hv = h22[s];
            den_l += p; x0 = fmaf(p, hv.x, x0); x1 = fmaf(p, hv.y, x1);
        }
    }
#pragma unroll
    for (int o = 32; o; o >>= 1) {
        den_l += __shfl_xor(den_l, o, 64);
        x0    += __shfl_xor(x0, o, 64);
        x1    += __shfl_xor(x1, o, 64);
    }
    if (j == 0) {
        const float inv = 1.f / (den_l + 1e-16f);
        out[n * 2 + 0] = x0 * inv + b2[0];
        out[n * 2 + 1] = x1 * inv + b2[1];
    }
}

extern "C" void kernel_launch(void* const* d_in, const int* in_sizes, int n_in,
                              void* d_out, int out_size, void* d_ws, size_t ws_size,
                              hipStream_t stream)
{
    const float* x    = (const float*)d_in[0];
    const int*   ei   = (const int*)d_in[1];
    const float* W1   = (const float*)d_in[2];
    const float* as1w = (const float*)d_in[3];
    const float* ad1w = (const float*)d_in[4];
    const float* b1   = (const float*)d_in[5];
    const float* W2   = (const float*)d_in[6];
    const float* as2w = (const float*)d_in[7];
    const float* ad2w = (const float*)d_in[8];
    const float* b2   = (const float*)d_in[9];
    float* out = (float*)d_out;

    float* ws = (float*)d_ws;
    size_t off = 0;
    unsigned* h1b = (unsigned*)(ws + off); off += (size_t)N_NODES * 32;  // 12.8 MB, node-major
    float* as1 = ws + off; off += N_NODES;
    float* ad1 = ws + off; off += N_NODES;
    float* h2  = ws + off; off += (size_t)N_NODES * 2;
    float* as2 = ws + off; off += N_NODES;
    float* ad2 = ws + off; off += N_NODES;
    int* gcur      = (int*)(ws + off); off += NBUCK * CPAD;              // 25 KB, zeroed
    unsigned* buf  = (unsigned*)(ws + off); off += (size_t)NBUCK * BUFCAP;  // 9.6 MB
    int* row_start = (int*)(ws + off); off += N_NODES + 1;
    int* csr       = (int*)(ws + off); off += N_EDGES;

    hipMemsetAsync(gcur, 0, NBUCK * CPAD * sizeof(int), stream);

    k_gemm1_bucketize <<<SB + GEMM_BLOCKS, 256, 0, stream>>>(
        x, W1, as1w, ad1w, h1b, as1, ad1, ei, gcur, buf);
    k_csr_build       <<<NBUCK, 1024, 0, stream>>>(gcur, buf, row_start, csr);
    k_agg1            <<<(N_NODES + 3) / 4, 256, 0, stream>>>(
        row_start, csr, as1, ad1, h1b, b1, W2, as2w, ad2w, h2, as2, ad2);
    k_agg2_wave       <<<(N_NODES + 3) / 4, 256, 0, stream>>>(row_start, csr, as2, ad2, h2, b2, out);
}

// Round 18
// 236.046 us; speedup vs baseline: 1.3363x; 1.0083x over previous
//
#include <hip/hip_runtime.h>
#include <math.h>

constexpr int N_NODES = 100000;
constexpr int N_EDGES = 1600000;
constexpr int F_IN    = 128;
constexpr int F_H     = 64;
constexpr float NEG_SLOPE = 0.2f;

constexpr int NBUCK  = (N_NODES + 255) / 256;  // 391 buckets of 256 dst nodes
constexpr int BUFCAP = 6144;                   // per-bucket stream cap (mean 4092, +32 sigma)
constexpr int LCAP   = 6144;
constexpr int CPAD   = 16;                     // gcur stride in ints: one 64B line per counter

// staged multisplit params
constexpr int SB   = 256;                      // bucketize-role blocks (dispatched FIRST)
constexpr int EPT  = 4;                        // edges per thread per round
constexpr int EPR  = 256 * EPT;                // 1024 edges per round
constexpr int G    = 16;                       // flush granularity = one 64B line
constexpr int BCAP = 32;                       // bin capacity: 15 carry + Poisson(2.62) round, P(ovf)~1e-12
constexpr int BSTR = 33;                       // bin row stride (words): (t*33+u)%32=(t+u)%32 -> conflict-free

constexpr int GEMM_BLOCKS = (N_NODES + 63) / 64;   // 1563 gemm-role blocks

__device__ inline float lrelu(float v) { return v > 0.f ? v : NEG_SLOPE * v; }
// bf16-pair unpack: u32 holds [lo = feature 2i, hi = feature 2i+1]
__device__ inline float blo(unsigned u) { return __uint_as_float(u << 16); }
__device__ inline float bhi(unsigned u) { return __uint_as_float(u & 0xFFFF0000u); }
// RNE float->bf16 (as high 16 bits)
__device__ inline unsigned bf16hi(float f) {
    unsigned u = __float_as_uint(f);
    return (u + 0x7FFFu + ((u >> 16) & 1u)) & 0xFFFF0000u;
}
__device__ inline unsigned bf16lo(float f) {
    unsigned u = __float_as_uint(f);
    return (u + 0x7FFFu + ((u >> 16) & 1u)) >> 16;
}

// ---------------- FUSED: bucketize (blocks 0..SB-1) + GEMM1 (blocks SB..) ----------------
// R16 lesson: the 75KB union capped the WHOLE kernel at 2 blocks/CU (occ 18%) and the stride-48
// bin rows gave ~32-way bank conflicts on flush (851K). BCAP=32 + stride-33 rows: 53.2KB LDS
// -> 3 blocks/CU, and flush bank = (t+u)%32 -> conflict-free.
__global__ __launch_bounds__(256) void k_gemm1_bucketize(
    const float* __restrict__ x, const float* __restrict__ W1,
    const float* __restrict__ a_s, const float* __restrict__ a_d,
    unsigned* __restrict__ h1b, float* __restrict__ as1, float* __restrict__ ad1,
    const int* __restrict__ ei, int* __restrict__ gcur, unsigned* __restrict__ buf)
{
    __shared__ union SM {
        struct { unsigned bin_buf[NBUCK][BSTR]; int bin_cnt[NBUCK]; } bk;  // ~53.2 KB
        struct { float vsP[4][64]; float vdP[4][64]; } gm;                  // 2 KB
    } sm;

    const int t = threadIdx.x;

    if (blockIdx.x < SB) {
        // ================= bucketize role =================
        for (int i = t; i < NBUCK; i += 256) sm.bk.bin_cnt[i] = 0;
        __syncthreads();

        const int per = N_EDGES / SB;               // 6250 exactly
        const int e0 = blockIdx.x * per;
        const int e1 = (blockIdx.x == SB - 1) ? N_EDGES : (e0 + per);

        int cs[EPT], cd[EPT];
#pragma unroll
        for (int q = 0; q < EPT; ++q) {
            const int i = e0 + q * 256 + t;
            cs[q] = (i < e1) ? ei[i] : -1;
            cd[q] = (i < e1) ? ei[N_EDGES + i] : 0;
        }

        for (int base = e0; base < e1; base += EPR) {
            int ls[EPT], ld[EPT];
#pragma unroll
            for (int q = 0; q < EPT; ++q) { ls[q] = cs[q]; ld[q] = cd[q]; }
            const int nbase = base + EPR;
            if (nbase < e1) {
#pragma unroll
                for (int q = 0; q < EPT; ++q) {
                    const int i = nbase + q * 256 + t;
                    cs[q] = (i < e1) ? ei[i] : -1;
                    cd[q] = (i < e1) ? ei[N_EDGES + i] : 0;
                }
            }
            // insert into LDS bins
#pragma unroll
            for (int q = 0; q < EPT; ++q) {
                if (ls[q] >= 0) {
                    const int b = ld[q] >> 8;
                    const int pos = atomicAdd(&sm.bk.bin_cnt[b], 1);
                    if (pos < BCAP)
                        sm.bk.bin_buf[b][pos] = ((unsigned)ls[q] << 8) | (unsigned)(ld[q] & 255);
                }
            }
            __syncthreads();
            // flush full 16-groups (aligned claims -> full-line writes; conflict-free reads)
            for (int bb = t; bb < NBUCK; bb += 256) {
                const int cnt = sm.bk.bin_cnt[bb];
                if (cnt >= G) {
                    const int take = cnt & ~(G - 1);
                    const int gbase = atomicAdd(&gcur[bb * CPAD], take);
                    if (gbase + take <= BUFCAP) {
                        unsigned* __restrict__ dst = buf + (size_t)bb * BUFCAP + gbase;
                        const int src0 = cnt - take;
                        for (int u = 0; u < take; u += 4) {
                            uint4 v;
                            v.x = sm.bk.bin_buf[bb][src0 + u];
                            v.y = sm.bk.bin_buf[bb][src0 + u + 1];
                            v.z = sm.bk.bin_buf[bb][src0 + u + 2];
                            v.w = sm.bk.bin_buf[bb][src0 + u + 3];
                            *(uint4*)(dst + u) = v;
                        }
                    }
                    sm.bk.bin_cnt[bb] = cnt - take;
                }
            }
            __syncthreads();
        }
        // drain partial bins
        for (int bb = t; bb < NBUCK; bb += 256) {
            const int cnt = sm.bk.bin_cnt[bb];
            if (cnt > 0) {
                const int gbase = atomicAdd(&gcur[bb * CPAD], cnt);
                if (gbase + cnt <= BUFCAP) {
                    unsigned* __restrict__ dst = buf + (size_t)bb * BUFCAP + gbase;
                    for (int u = 0; u < cnt; ++u) dst[u] = sm.bk.bin_buf[bb][u];
                }
            }
        }
        return;
    }

    // ================= gemm1 role =================
    const int lane = t & 63;
    const int w    = __builtin_amdgcn_readfirstlane(t >> 6);  // SGPR wave id
    const int fo   = w * 16;                                  // feature offset (wave-uniform)
    const int row  = (blockIdx.x - SB) * 64 + lane;
    const bool valid = row < N_NODES;

    float acc[16];
#pragma unroll
    for (int i = 0; i < 16; ++i) acc[i] = 0.f;

    if (valid) {
        const float4* __restrict__ xr = (const float4*)(x + (size_t)row * F_IN);
        float4 xv = xr[0];
        for (int k4 = 0; k4 < F_IN / 4; ++k4) {
            const float4 xn = xr[(k4 + 1) & (F_IN / 4 - 1)];   // prefetch (wraps harmlessly)
            const float* __restrict__ wk = W1 + (size_t)k4 * 4 * F_H + fo;  // wave-uniform
#pragma unroll
            for (int kk = 0; kk < 4; ++kk) {
                const float xs = (kk == 0) ? xv.x : (kk == 1) ? xv.y : (kk == 2) ? xv.z : xv.w;
                const float* __restrict__ ws = wk + kk * F_H;   // scalar loads (SGPR base)
#pragma unroll
                for (int i = 0; i < 16; ++i)
                    acc[i] = fmaf(xs, ws[i], acc[i]);
            }
            xv = xn;
        }
    }

    // partial alphas over this wave's 16 features (fp32, pre-rounding)
    float vs = 0.f, vd = 0.f;
#pragma unroll
    for (int i = 0; i < 16; ++i) {
        vs = fmaf(acc[i], a_s[fo + i], vs);
        vd = fmaf(acc[i], a_d[fo + i], vd);
    }
    sm.gm.vsP[w][lane] = vs;
    sm.gm.vdP[w][lane] = vd;
    __syncthreads();
    if (w == 0 && valid) {
        as1[row] = sm.gm.vsP[0][lane] + sm.gm.vsP[1][lane] + sm.gm.vsP[2][lane] + sm.gm.vsP[3][lane];
        ad1[row] = sm.gm.vdP[0][lane] + sm.gm.vdP[1][lane] + sm.gm.vdP[2][lane] + sm.gm.vdP[3][lane];
    }

    if (valid) {
        // pack this wave's 16 features -> 8 u32 (bf16 RNE), write slice [8w, 8w+8)
        unsigned up[8];
#pragma unroll
        for (int i = 0; i < 8; ++i)
            up[i] = bf16lo(acc[2 * i]) | bf16hi(acc[2 * i + 1]);
        uint4* __restrict__ hr = (uint4*)(h1b + (size_t)row * 32 + w * 8);
        hr[0] = make_uint4(up[0], up[1], up[2], up[3]);
        hr[1] = make_uint4(up[4], up[5], up[6], up[7]);
    }
}

// ---------------- Per-bucket CSR build in LDS + inlined bucket-prefix scan ----------------
__global__ __launch_bounds__(1024) void k_csr_build(
    const int* __restrict__ gcur, const unsigned* __restrict__ buf,
    int* __restrict__ row_start, int* __restrict__ csr)
{
    __shared__ int lcsr[LCAP];      // 24 KB
    __shared__ int hist[256];
    __shared__ int lstart[257];
    __shared__ int lcur[256];
    __shared__ int redsm[16];
    __shared__ int gb_sm;

    const int b  = blockIdx.x;
    const int t  = threadIdx.x;
    const int nd = min(256, N_NODES - (b << 8));
    const int m  = min(gcur[b * CPAD], BUFCAP);
    const unsigned* __restrict__ sb = buf + (size_t)b * BUFCAP;

    // exclusive prefix over buckets < b
    int part = 0;
    for (int i = t; i < b; i += 1024) part += min(gcur[i * CPAD], BUFCAP);
#pragma unroll
    for (int o = 32; o; o >>= 1) part += __shfl_xor(part, o, 64);
    if ((t & 63) == 0) redsm[t >> 6] = part;
    if (t < 256) hist[t] = 0;
    __syncthreads();
    if (t == 0) {
        int s = 0;
#pragma unroll
        for (int i = 0; i < 16; ++i) s += redsm[i];
        gb_sm = s;
    }
    __syncthreads();

    for (int i = t; i < m; i += 1024) atomicAdd(&hist[sb[i] & 255], 1);
    __syncthreads();

    for (int o = 1; o < 256; o <<= 1) {
        int a = 0;
        if (t < 256 && t >= o) a = hist[t - o];
        __syncthreads();
        if (t < 256) hist[t] += a;
        __syncthreads();
    }
    if (t < 256) { lstart[t + 1] = hist[t]; lcur[t] = 0; }
    if (t == 0) lstart[0] = 0;
    __syncthreads();

    for (int i = t; i < m; i += 1024) {
        const unsigned v = sb[i];
        const int dl = v & 255;
        const int p  = atomicAdd(&lcur[dl], 1);
        const int pp = lstart[dl] + p;
        if (pp < LCAP) lcsr[pp] = (int)(v >> 8);
    }
    __syncthreads();

    const int gb   = gb_sm;
    const int mtot = lstart[256];
    for (int i = t; i < mtot; i += 1024) csr[gb + i] = lcsr[i];
    if (t < nd) row_start[(b << 8) + t + 1] = gb + lstart[t + 1];
    if (b == 0 && t == 0) row_start[0] = 0;
}

// ---------------- Layer-1 aggregate: wave per dst, degree-guarded slot blocks ----------------
// (R15-verified: 56us.) Guards at 16/24/32 (wave-uniform); pad lanes carry sj=n, pj=0 ->
// boundaries exact. No-max softmax (shift-invariant; alphas O(1..10), fp32-safe).
__global__ __launch_bounds__(256, 4) void k_agg1(
    const int* __restrict__ row_start, const int* __restrict__ csr,
    const float* __restrict__ as1, const float* __restrict__ ad1,
    const unsigned* __restrict__ h1b,
    const float* __restrict__ b1, const float* __restrict__ W2,
    const float* __restrict__ a_s2, const float* __restrict__ a_d2,
    float* __restrict__ h2, float* __restrict__ as2, float* __restrict__ ad2)
{
    const int n = blockIdx.x * 4 + (threadIdx.x >> 6);
    const int j = threadIdx.x & 63;
    if (n >= N_NODES) return;

    const int g  = j >> 3;        // edge-phase group 0..7
    const int oq = (j & 7) << 2;  // u32 offset in row (4 u32 = 8 features)

    const int r0  = row_start[n];
    const int deg = row_start[n + 1] - r0;   // real in-edges; +1 implicit self
    const float ad = ad1[n];

    float acc0[8], acc1[8];
#pragma unroll
    for (int i = 0; i < 8; ++i) { acc0[i] = 0.f; acc1[i] = 0.f; }
    float den_l = 0.f;

#define FMA8(ACC, P, U)                                            \
    ACC[0] = fmaf(P, blo(U.x), ACC[0]); ACC[1] = fmaf(P, bhi(U.x), ACC[1]); \
    ACC[2] = fmaf(P, blo(U.y), ACC[2]); ACC[3] = fmaf(P, bhi(U.y), ACC[3]); \
    ACC[4] = fmaf(P, blo(U.z), ACC[4]); ACC[5] = fmaf(P, bhi(U.z), ACC[5]); \
    ACC[6] = fmaf(P, blo(U.w), ACC[6]); ACC[7] = fmaf(P, bhi(U.w), ACC[7]);
#define LD8(S) (*(const uint4*)(h1b + ((size_t)(S) << 5) + oq))

    if (deg <= 63) {               // fast path: edges + self in one wave chunk
        int sj = n;                // lanes >= deg: self row (lane 'deg' IS the self edge)
        if (j < deg) sj = csr[r0 + j];
        const float aj = as1[sj];                 // gather, issued first (valid for pads too)
        // slots 0-15: unconditional (covers tot <= 16, 47% of nodes entirely)
        const int s0 = __shfl(sj, g,      64);
        const int s1 = __shfl(sj, 8 + g,  64);
        const uint4 u0 = LD8(s0);
        const uint4 u1 = LD8(s1);
        // p while gathers are in flight (waits only on aj)
        float pj = 0.f;
        if (j <= deg) pj = __expf(lrelu(aj + ad));
        den_l = pj;
        const float p0 = __shfl(pj, g,      64);
        const float p1 = __shfl(pj, 8 + g,  64);

        const int tot = deg + 1;
        const bool t16 = tot > 16, t24 = tot > 24, t32 = tot > 32;
        // guarded loads issued early, FMAs later (keep loads in flight across p0/p1 FMAs)
        int s2, s3; uint4 u2, u3; float p2, p3;
        if (t16) { s2 = __shfl(sj, 16 + g, 64); u2 = LD8(s2); p2 = __shfl(pj, 16 + g, 64); }
        if (t24) { s3 = __shfl(sj, 24 + g, 64); u3 = LD8(s3); p3 = __shfl(pj, 24 + g, 64); }
        FMA8(acc0, p0, u0) FMA8(acc1, p1, u1)
        if (t16) { FMA8(acc0, p2, u2) }
        if (t24) { FMA8(acc1, p3, u3) }
        if (t32) {                 // rare (~2e-4 of nodes): loop the remaining slots
            for (int base = 32; base < tot; base += 8) {
                const int   sA = __shfl(sj, base + g, 64);   // src lane <= 63
                const float pA = __shfl(pj, base + g, 64);
                const uint4 ua = LD8(sA);
                FMA8(acc0, pA, ua)
            }
        }
    } else {                       // generic chunked path + explicit self (stat. never taken)
        {   // self edge: group 0 lanes cover all 8 feature-octs
            const float ps = __expf(lrelu(as1[n] + ad));
            if (j == 0) den_l += ps;
            if (g == 0) {
                const uint4 uv = LD8(n);
                FMA8(acc0, ps, uv)
            }
        }
        for (int cb = r0; cb < r0 + deg; cb += 64) {
            const int cnt = min(64, r0 + deg - cb);   // wave-uniform
            int sj = 0; float pj = 0.f;               // pad lanes: valid row 0, p = 0
            if (j < cnt) { sj = csr[cb + j]; pj = __expf(lrelu(as1[sj] + ad)); }
            den_l += pj;
            for (int base = 0; base < cnt; base += 16) {
                const int   sA = __shfl(sj, base + g, 64);
                const float pA = __shfl(pj, base + g, 64);
                const uint4 ua = LD8(sA);
                FMA8(acc0, pA, ua)
                if (base + 8 < cnt) {
                    const int   sB = __shfl(sj, base + 8 + g, 64);
                    const float pB = __shfl(pj, base + 8 + g, 64);
                    const uint4 ub = LD8(sB);
                    FMA8(acc1, pB, ub)
                }
            }
        }
    }
#undef FMA8
#undef LD8

    float den = den_l;
#pragma unroll
    for (int o = 32; o; o >>= 1) den += __shfl_xor(den, o, 64);

    // merge unroll chains, then sum the 8 edge-groups (lanes with equal j&7)
#pragma unroll
    for (int i = 0; i < 8; ++i) acc0[i] += acc1[i];
#pragma unroll
    for (int o = 8; o <= 32; o <<= 1) {
#pragma unroll
        for (int i = 0; i < 8; ++i) acc0[i] += __shfl_xor(acc0[i], o, 64);
    }

    // layer-1 epilogue + 64x2 layer-2 GEMM + alpha2 (features ob..ob+7 per lane)
    const float inv = 1.f / (den + 1e-16f);
    const int ob = (j & 7) << 3;
    const float4 b0 = *(const float4*)(b1 + ob);
    const float4 b4 = *(const float4*)(b1 + ob + 4);
    float v[8];
    v[0] = acc0[0] * inv + b0.x; v[1] = acc0[1] * inv + b0.y;
    v[2] = acc0[2] * inv + b0.z; v[3] = acc0[3] * inv + b0.w;
    v[4] = acc0[4] * inv + b4.x; v[5] = acc0[5] * inv + b4.y;
    v[6] = acc0[6] * inv + b4.z; v[7] = acc0[7] * inv + b4.w;
#pragma unroll
    for (int i = 0; i < 8; ++i) v[i] = v[i] > 0.f ? v[i] : 0.f;

    const float4* __restrict__ wq = (const float4*)(W2 + 2 * ob);  // rows ob..ob+7, 2 cols
    const float4 w0 = wq[0], w1 = wq[1], w2 = wq[2], w3 = wq[3];
    float c0 = v[0] * w0.x + v[1] * w0.z + v[2] * w1.x + v[3] * w1.z
             + v[4] * w2.x + v[5] * w2.z + v[6] * w3.x + v[7] * w3.z;
    float c1 = v[0] * w0.y + v[1] * w0.w + v[2] * w1.y + v[3] * w1.w
             + v[4] * w2.y + v[5] * w2.w + v[6] * w3.y + v[7] * w3.w;
#pragma unroll
    for (int o = 1; o <= 4; o <<= 1) {   // sum the 8 feature-octs within the group
        c0 += __shfl_xor(c0, o, 64);
        c1 += __shfl_xor(c1, o, 64);
    }
    if (j == 0) {
        h2[n * 2 + 0] = c0;
        h2[n * 2 + 1] = c1;
        as2[n] = c0 * a_s2[0] + c1 * a_s2[1];
        ad2[n] = c0 * a_d2[0] + c1 * a_d2[1];
    }
}

// ---------------- Layer-2 aggregate: wave per dst, no-max softmax, parallel dual gathers --------
__global__ __launch_bounds__(256) void k_agg2_wave(
    const int* __restrict__ row_start, const int* __restrict__ csr,
    const float* __restrict__ as2, const float* __restrict__ ad2,
    const float* __restrict__ h2, const float* __restrict__ b2,
    float* __restrict__ out)
{
    const int n = blockIdx.x * 4 + (threadIdx.x >> 6);
    const int j = threadIdx.x & 63;
    if (n >= N_NODES) return;
    const int r0  = row_start[n];
    const int deg = row_start[n + 1] - r0;
    const float ad = ad2[n];
    const float2* __restrict__ h22 = (const float2*)h2;

    float den_l = 0.f, x0 = 0.f, x1 = 0.f;
    if (deg <= 63) {
        int sj = n;                                 // lanes >= deg: self row
        if (j < deg) sj = csr[r0 + j];
        const float  aj = as2[sj];                  // both gathers in flight together
        const float2 hv = h22[sj];
        float p = 0.f;
        if (j <= deg) p = __expf(lrelu(aj + ad));
        den_l = p; x0 = p * hv.x; x1 = p * hv.y;
    } else {
        if (j == 0) {   // self edge
            const float p = __expf(lrelu(as2[n] + ad));
            const float2 hv = h22[n];
            den_l = p; x0 = p * hv.x; x1 = p * hv.y;
        }
        for (int idx = r0 + j; idx < r0 + deg; idx += 64) {
            const int s = csr[idx];
            const float p = __expf(lrelu(as2[s] + ad));
            const float2 hv = h22[s];
            den_l += p; x0 = fmaf(p, hv.x, x0); x1 = fmaf(p, hv.y, x1);
        }
    }
#pragma unroll
    for (int o = 32; o; o >>= 1) {
        den_l += __shfl_xor(den_l, o, 64);
        x0    += __shfl_xor(x0, o, 64);
        x1    += __shfl_xor(x1, o, 64);
    }
    if (j == 0) {
        const float inv = 1.f / (den_l + 1e-16f);
        out[n * 2 + 0] = x0 * inv + b2[0];
        out[n * 2 + 1] = x1 * inv + b2[1];
    }
}

extern "C" void kernel_launch(void* const* d_in, const int* in_sizes, int n_in,
                              void* d_out, int out_size, void* d_ws, size_t ws_size,
                              hipStream_t stream)
{
    const float* x    = (const float*)d_in[0];
    const int*   ei   = (const int*)d_in[1];
    const float* W1   = (const float*)d_in[2];
    const float* as1w = (const float*)d_in[3];
    const float* ad1w = (const float*)d_in[4];
    const float* b1   = (const float*)d_in[5];
    const float* W2   = (const float*)d_in[6];
    const float* as2w = (const float*)d_in[7];
    const float* ad2w = (const float*)d_in[8];
    const float* b2   = (const float*)d_in[9];
    float* out = (float*)d_out;

    float* ws = (float*)d_ws;
    size_t off = 0;
    unsigned* h1b = (unsigned*)(ws + off); off += (size_t)N_NODES * 32;  // 12.8 MB, node-major
    float* as1 = ws + off; off += N_NODES;
    float* ad1 = ws + off; off += N_NODES;
    float* h2  = ws + off; off += (size_t)N_NODES * 2;
    float* as2 = ws + off; off += N_NODES;
    float* ad2 = ws + off; off += N_NODES;
    int* gcur      = (int*)(ws + off); off += NBUCK * CPAD;              // 25 KB, zeroed
    unsigned* buf  = (unsigned*)(ws + off); off += (size_t)NBUCK * BUFCAP;  // 9.6 MB
    int* row_start = (int*)(ws + off); off += N_NODES + 1;
    int* csr       = (int*)(ws + off); off += N_EDGES;

    hipMemsetAsync(gcur, 0, NBUCK * CPAD * sizeof(int), stream);

    k_gemm1_bucketize <<<SB + GEMM_BLOCKS, 256, 0, stream>>>(
        x, W1, as1w, ad1w, h1b, as1, ad1, ei, gcur, buf);
    k_csr_build       <<<NBUCK, 1024, 0, stream>>>(gcur, buf, row_start, csr);
    k_agg1            <<<(N_NODES + 3) / 4, 256, 0, stream>>>(
        row_start, csr, as1, ad1, h1b, b1, W2, as2w, ad2w, h2, as2, ad2);
    k_agg2_wave       <<<(N_NODES + 3) / 4, 256, 0, stream>>>(row_start, csr, as2, ad2, h2, b2, out);
}